// Round 1
// baseline (5928.526 us; speedup 1.0000x reference)
//
#include <hip/hip_runtime.h>

#define ROI_SCALE (1.0f/32.0f)

// ---------------- block reduce (sum, sumsq) over 256 threads ----------------
__device__ inline void block_reduce2(float& s, float& ss) {
    #pragma unroll
    for (int o = 32; o > 0; o >>= 1) {
        s  += __shfl_down(s, o);
        ss += __shfl_down(ss, o);
    }
    __shared__ float red[8];
    const int t = threadIdx.x;
    if ((t & 63) == 0) { red[t >> 6] = s; red[4 + (t >> 6)] = ss; }
    __syncthreads();
    s  = red[0] + red[1] + red[2] + red[3];
    ss = red[4] + red[5] + red[6] + red[7];
}

// ---------------- generic fp32 tiled GEMM:  C[M][N] = A(MxK) * B^T  (B is [N][K]) ----
// AMODE: 0 = A row-major [M][K] (lda)
//        1 = A col-major [K][M] (lda = per-k row stride)
//        2 = im2col over r_cl [Nroi][49][1024]; k = tap*1024 + ic
// EPI:   0 none, 1 +bias(P1), 2 relu(x+bias(P1)), 3 relu(x*P1[n] + P2[n])
// CMODE: 0 C row-major (ldc), 1 conv scatter C[nroi][oc*49+sp], 2 column-sum atomicAdd C[n]
template<int AMODE, int EPI, int CMODE>
__global__ __launch_bounds__(256)
void gemm_f32(const float* __restrict__ A, const float* __restrict__ B,
              const float* __restrict__ P1, const float* __restrict__ P2,
              float* __restrict__ C,
              int M, int N, int K, int lda, int ldb, int ldc,
              long strideA, long strideC)
{
    __shared__ float As[16][68];
    __shared__ float Bs[16][68];
    const int t  = threadIdx.x;
    const int tx = t & 15, ty = t >> 4;
    const int m0 = blockIdx.y * 64, n0 = blockIdx.x * 64;
    if (strideA) A += (long)blockIdx.z * strideA;
    if (strideC) C += (long)blockIdx.z * strideC;

    float acc[4][4] = {};

    const int ar  = t >> 2,  akk = (t & 3) * 4;   // AMODE 0/2 + B staging
    const int kr  = t >> 4,  am  = (t & 15) * 4;  // AMODE 1 staging

    for (int k0 = 0; k0 < K; k0 += 16) {
        __syncthreads();
        // ---- stage A tile (64 m x 16 k), transposed into As[k][m] ----
        if (AMODE == 0) {
            const float4 av = *reinterpret_cast<const float4*>(&A[(long)(m0 + ar) * lda + k0 + akk]);
            As[akk+0][ar] = av.x; As[akk+1][ar] = av.y; As[akk+2][ar] = av.z; As[akk+3][ar] = av.w;
        } else if (AMODE == 1) {
            const float4 av = *reinterpret_cast<const float4*>(&A[(long)(k0 + kr) * lda + m0 + am]);
            *reinterpret_cast<float4*>(&As[kr][am]) = av;
        } else {
            const int m = m0 + ar;
            const int nroi = m / 49, sp = m % 49;
            const int k = k0 + akk;
            const int tap = k >> 10, ic = k & 1023;
            const int yy = sp / 7 + tap / 3 - 1;
            const int xx = sp % 7 + tap % 3 - 1;
            float4 av = make_float4(0.f, 0.f, 0.f, 0.f);
            if (yy >= 0 && yy < 7 && xx >= 0 && xx < 7)
                av = *reinterpret_cast<const float4*>(&A[((long)nroi * 49 + yy * 7 + xx) * 1024 + ic]);
            As[akk+0][ar] = av.x; As[akk+1][ar] = av.y; As[akk+2][ar] = av.z; As[akk+3][ar] = av.w;
        }
        // ---- stage B tile (64 n x 16 k), transposed into Bs[k][n] ----
        {
            const float4 bv = *reinterpret_cast<const float4*>(&B[(long)(n0 + ar) * ldb + k0 + akk]);
            Bs[akk+0][ar] = bv.x; Bs[akk+1][ar] = bv.y; Bs[akk+2][ar] = bv.z; Bs[akk+3][ar] = bv.w;
        }
        __syncthreads();
        // ---- 4x4 micro-kernel ----
        #pragma unroll
        for (int k = 0; k < 16; ++k) {
            const float4 a4 = *reinterpret_cast<const float4*>(&As[k][ty * 4]);
            const float4 b4 = *reinterpret_cast<const float4*>(&Bs[k][tx * 4]);
            const float a[4] = {a4.x, a4.y, a4.z, a4.w};
            const float b[4] = {b4.x, b4.y, b4.z, b4.w};
            #pragma unroll
            for (int i = 0; i < 4; ++i)
                #pragma unroll
                for (int j = 0; j < 4; ++j)
                    acc[i][j] = fmaf(a[i], b[j], acc[i][j]);
        }
    }

    // ---- epilogue ----
    float vout[4][4];
    #pragma unroll
    for (int i = 0; i < 4; ++i) {
        #pragma unroll
        for (int j = 0; j < 4; ++j) {
            float v = acc[i][j];
            const int n = n0 + tx * 4 + j;
            if (EPI == 1)      v += P1[n];
            else if (EPI == 2) v = fmaxf(v + P1[n], 0.f);
            else if (EPI == 3) v = fmaxf(v * P1[n] + P2[n], 0.f);
            vout[i][j] = v;
        }
    }
    if (CMODE == 0) {
        #pragma unroll
        for (int i = 0; i < 4; ++i) {
            const long m = m0 + ty * 4 + i;
            #pragma unroll
            for (int j = 0; j < 4; ++j)
                C[m * ldc + n0 + tx * 4 + j] = vout[i][j];
        }
    } else if (CMODE == 1) {
        #pragma unroll
        for (int i = 0; i < 4; ++i) {
            const int m = m0 + ty * 4 + i;
            const int nroi = m / 49, sp = m % 49;
            #pragma unroll
            for (int j = 0; j < 4; ++j)
                C[(long)nroi * 12544 + (n0 + tx * 4 + j) * 49 + sp] = vout[i][j];
        }
    } else {
        __syncthreads();
        float* red = &As[0][0];
        #pragma unroll
        for (int j = 0; j < 4; ++j)
            red[ty * 64 + tx * 4 + j] = vout[0][j] + vout[1][j] + vout[2][j] + vout[3][j];
        __syncthreads();
        if (t < 64) {
            float s = 0.f;
            #pragma unroll
            for (int g = 0; g < 16; ++g) s += red[g * 64 + t];
            atomicAdd(&C[n0 + t], s);
        }
    }
}

// ---------------- ROIAlignV2 (aligned=true), 2x2 samples/bin, channels-last ------------
// x_cl [8][256][1024] (hw-major, channel-last), boxes [512][4], out r_cl [512][49][1024]
__global__ __launch_bounds__(256)
void roialign_kernel(const float* __restrict__ x_cl, const float* __restrict__ boxes,
                     float* __restrict__ r_cl)
{
    const int blk = blockIdx.x;          // n*49 + bin
    const int n = blk / 49, bin = blk % 49;
    const int py = bin / 7, px = bin % 7;
    const int b = n >> 6;
    const float* roi = boxes + n * 4;
    const float x1 = roi[0] * ROI_SCALE - 0.5f;
    const float y1 = roi[1] * ROI_SCALE - 0.5f;
    const float bw = (roi[2] - roi[0]) * ROI_SCALE * (1.0f / 7.0f);
    const float bh = (roi[3] - roi[1]) * ROI_SCALE * (1.0f / 7.0f);
    const int t = threadIdx.x;

    float acc[4] = {0.f, 0.f, 0.f, 0.f};
    #pragma unroll
    for (int sy = 0; sy < 2; ++sy) {
        #pragma unroll
        for (int sx = 0; sx < 2; ++sx) {
            const float yv = y1 + bh * ((float)(py * 2 + sy) + 0.5f) * 0.5f;
            const float xv = x1 + bw * ((float)(px * 2 + sx) + 0.5f) * 0.5f;
            const bool vy = (yv >= -1.0f) && (yv <= 16.0f);
            const bool vx = (xv >= -1.0f) && (xv <= 16.0f);
            if (!(vy && vx)) continue;
            float yc = fmaxf(yv, 0.f);
            int yl = (int)floorf(yc);
            int yh; if (yl >= 15) { yl = 15; yc = 15.f; yh = 15; } else yh = yl + 1;
            const float wy = yc - (float)yl;
            float xc = fmaxf(xv, 0.f);
            int xl = (int)floorf(xc);
            int xh; if (xl >= 15) { xl = 15; xc = 15.f; xh = 15; } else xh = xl + 1;
            const float wx = xc - (float)xl;

            const float w00 = (1.f - wy) * (1.f - wx), w01 = (1.f - wy) * wx;
            const float w10 = wy * (1.f - wx),         w11 = wy * wx;
            const float* p00 = x_cl + ((long)b * 256 + yl * 16 + xl) * 1024;
            const float* p01 = x_cl + ((long)b * 256 + yl * 16 + xh) * 1024;
            const float* p10 = x_cl + ((long)b * 256 + yh * 16 + xl) * 1024;
            const float* p11 = x_cl + ((long)b * 256 + yh * 16 + xh) * 1024;
            #pragma unroll
            for (int cc = 0; cc < 4; ++cc) {
                const int c = t + cc * 256;
                acc[cc] += w00 * p00[c] + w01 * p01[c] + w10 * p10[c] + w11 * p11[c];
            }
        }
    }
    float* o = r_cl + ((long)n * 49 + bin) * 1024;
    #pragma unroll
    for (int cc = 0; cc < 4; ++cc) o[t + cc * 256] = acc[cc] * 0.25f;
}

// ---------------- pack conv weights (tap-major K) + fold BN into scale/shift ----------
__global__ __launch_bounds__(256)
void pack_conv(const float* __restrict__ conv_w, const float* __restrict__ conv_b,
               const float* __restrict__ bn_g, const float* __restrict__ bn_b,
               const float* __restrict__ bn_m, const float* __restrict__ bn_v,
               float* __restrict__ wpack, float* __restrict__ scale, float* __restrict__ shift)
{
    const long idx = (long)blockIdx.x * 256 + threadIdx.x;
    if (idx < (long)256 * 9216) {
        const int oc = (int)(idx / 9216), k = (int)(idx % 9216);
        const int tap = k >> 10, ic = k & 1023;
        wpack[idx] = conv_w[(long)oc * 9216 + ic * 9 + tap];
    }
    if (idx < 256) {
        const float s = bn_g[idx] * rsqrtf(bn_v[idx] + 1e-5f);
        scale[idx] = s;
        shift[idx] = (conv_b[idx] - bn_m[idx]) * s + bn_b[idx];
    }
}

// ---------------- LayerNorm over 1024 -> feats[:, :1024] ----------------
__global__ __launch_bounds__(256)
void ln1_kernel(const float* __restrict__ in, const float* __restrict__ g,
                const float* __restrict__ b, float* __restrict__ feats)
{
    const int n = blockIdx.x, t = threadIdx.x;
    const float4 v = *reinterpret_cast<const float4*>(in + (long)n * 1024 + t * 4);
    float s  = v.x + v.y + v.z + v.w;
    float ss = v.x*v.x + v.y*v.y + v.z*v.z + v.w*v.w;
    block_reduce2(s, ss);
    const float mu  = s * (1.f / 1024.f);
    const float var = ss * (1.f / 1024.f) - mu * mu;
    const float r   = rsqrtf(var + 1e-5f);
    float* o = feats + (long)n * 1280 + t * 4;
    const float* gp = g + t * 4;
    const float* bp = b + t * 4;
    o[0] = (v.x - mu) * r * gp[0] + bp[0];
    o[1] = (v.y - mu) * r * gp[1] + bp[1];
    o[2] = (v.z - mu) * r * gp[2] + bp[2];
    o[3] = (v.w - mu) * r * gp[3] + bp[3];
}

// ---------------- box branch: (nb*2-1) @ box_w^T + b -> LN(256) -> feats[:,1024:] -----
__global__ __launch_bounds__(256)
void box_kernel(const float* __restrict__ nb, const float* __restrict__ bw,
                const float* __restrict__ bb, const float* __restrict__ g,
                const float* __restrict__ be, float* __restrict__ feats)
{
    const int n = blockIdx.x, j = threadIdx.x;
    const float4 q = *reinterpret_cast<const float4*>(nb + n * 4);
    const float4 w = *reinterpret_cast<const float4*>(bw + j * 4);
    const float v = (q.x * 2.f - 1.f) * w.x + (q.y * 2.f - 1.f) * w.y
                  + (q.z * 2.f - 1.f) * w.z + (q.w * 2.f - 1.f) * w.w + bb[j];
    float s = v, ss = v * v;
    block_reduce2(s, ss);
    const float mu  = s * (1.f / 256.f);
    const float var = ss * (1.f / 256.f) - mu * mu;
    feats[(long)n * 1280 + 1024 + j] = (v - mu) * rsqrtf(var + 1e-5f) * g[j] + be[j];
}

// ---------------- pair expansion: h1[a*64+b][c] = relu(U[b]+V[a]+g1_b) ----------------
__global__ __launch_bounds__(256)
void pair_kernel(const float* __restrict__ U, const float* __restrict__ V,
                 const float* __restrict__ g1_b, float* __restrict__ h1, int img)
{
    const int pair = blockIdx.y;
    const int a = pair >> 6, b = pair & 63;
    const int col = blockIdx.x * 256 + threadIdx.x;
    const float v = U[(long)(img * 64 + b) * 1280 + col]
                  + V[(long)(img * 64 + a) * 1280 + col] + g1_b[col];
    h1[(long)pair * 1280 + col] = fmaxf(v, 0.f);
}

__global__ void zero_kernel(float* __restrict__ p, int n) {
    const int i = blockIdx.x * 256 + threadIdx.x;
    if (i < n) p[i] = 0.f;
}

// =======================================================================================
extern "C" void kernel_launch(void* const* d_in, const int* in_sizes, int n_in,
                              void* d_out, int out_size, void* d_ws, size_t ws_size,
                              hipStream_t stream)
{
    const float* im_feat = (const float*)d_in[0];
    const float* boxes   = (const float*)d_in[1];
    const float* nboxes  = (const float*)d_in[2];
    const float* proj_w  = (const float*)d_in[3];
    const float* proj_b  = (const float*)d_in[4];
    const float* conv_w  = (const float*)d_in[5];
    const float* conv_b  = (const float*)d_in[6];
    const float* bn_g    = (const float*)d_in[7];
    const float* bn_b    = (const float*)d_in[8];
    const float* bn_m    = (const float*)d_in[9];
    const float* bn_v    = (const float*)d_in[10];
    const float* fc_w    = (const float*)d_in[11];
    const float* fc_b    = (const float*)d_in[12];
    const float* ln1_g   = (const float*)d_in[13];
    const float* ln1_b   = (const float*)d_in[14];
    const float* box_w   = (const float*)d_in[15];
    const float* box_b   = (const float*)d_in[16];
    const float* ln2_g   = (const float*)d_in[17];
    const float* ln2_b   = (const float*)d_in[18];
    const float* g1_w    = (const float*)d_in[19];
    const float* g1_b    = (const float*)d_in[20];
    const float* g2_w    = (const float*)d_in[21];
    const float* g2_b    = (const float*)d_in[22];
    const float* g3_w    = (const float*)d_in[23];
    const float* g3_b    = (const float*)d_in[24];
    float* out = (float*)d_out;

    float* ws      = (float*)d_ws;
    float* x_cl    = ws;                    // [8][256][1024]        2,097,152
    float* r_cl    = x_cl + 2097152;        // [512][49][1024]      25,690,112
    float* convout = r_cl + 25690112;       // [512][256*49]         6,422,528
    float* fc_out  = convout + 6422528;     // [512][1024]             524,288
    float* feats   = fc_out + 524288;       // [512][1280]             655,360
    float* Ubuf    = feats + 655360;        // [512][1280]
    float* Vbuf    = Ubuf + 655360;         // [512][1280]
    float* wpack   = Vbuf + 655360;         // [256][9216]           2,359,296
    float* scale   = wpack + 2359296;       // [256]
    float* shift   = scale + 256;           // [256]
    float* h1      = shift + 256;           // [4096][1280]          5,242,880
    float* h2      = h1 + 5242880;          // [4096][1280]
    (void)ws_size; (void)in_sizes; (void)n_in; (void)out_size;

    // output is accumulated via atomics in g3 epilogue -> zero it first
    zero_kernel<<<40, 256, 0, stream>>>(out, 10240);

    // pack conv weights (tap-major K) + BN fold
    pack_conv<<<(2359296 + 255) / 256, 256, 0, stream>>>(conv_w, conv_b, bn_g, bn_b, bn_m, bn_v,
                                                         wpack, scale, shift);

    // 1x1 projection: per-batch GEMM, A col-major [K=2048][M=256hw], out channels-last
    gemm_f32<1, 1, 0><<<dim3(16, 4, 8), 256, 0, stream>>>(
        im_feat, proj_w, proj_b, nullptr, x_cl,
        256, 1024, 2048, 256, 2048, 1024, (long)2048 * 256, (long)256 * 1024);

    // ROIAlign -> r_cl [512][49][1024]
    roialign_kernel<<<512 * 49, 256, 0, stream>>>(x_cl, boxes, r_cl);

    // conv3x3 + BN + ReLU as im2col GEMM: M=25088, N=256, K=9216
    gemm_f32<2, 3, 1><<<dim3(4, 392, 1), 256, 0, stream>>>(
        r_cl, wpack, scale, shift, convout,
        25088, 256, 9216, 0, 9216, 0, 0L, 0L);

    // FC + ReLU: M=512, N=1024, K=12544
    gemm_f32<0, 2, 0><<<dim3(16, 8, 1), 256, 0, stream>>>(
        convout, fc_w, fc_b, nullptr, fc_out,
        512, 1024, 12544, 12544, 12544, 1024, 0L, 0L);

    // LN1 -> feats[:, :1024]
    ln1_kernel<<<512, 256, 0, stream>>>(fc_out, ln1_g, ln1_b, feats);

    // box branch -> feats[:, 1024:1280]
    box_kernel<<<512, 256, 0, stream>>>(nboxes, box_w, box_b, ln2_g, ln2_b, feats);

    // relation g1 decomposition: U = feats @ g1_w[:, :1280]^T, V = feats @ g1_w[:, 1280:]^T
    gemm_f32<0, 0, 0><<<dim3(20, 8, 1), 256, 0, stream>>>(
        feats, g1_w, nullptr, nullptr, Ubuf,
        512, 1280, 1280, 1280, 2560, 1280, 0L, 0L);
    gemm_f32<0, 0, 0><<<dim3(20, 8, 1), 256, 0, stream>>>(
        feats, g1_w + 1280, nullptr, nullptr, Vbuf,
        512, 1280, 1280, 1280, 2560, 1280, 0L, 0L);

    // per-image relation: h1 = relu(U[b]+V[a]+b1); h2 = relu(h1@g2^T+b2);
    // out[img] += colsum(relu(h2@g3^T+b3))   (sum fused into g3 epilogue)
    for (int img = 0; img < 8; ++img) {
        pair_kernel<<<dim3(5, 4096), 256, 0, stream>>>(Ubuf, Vbuf, g1_b, h1, img);
        gemm_f32<0, 2, 0><<<dim3(20, 64, 1), 256, 0, stream>>>(
            h1, g2_w, g2_b, nullptr, h2,
            4096, 1280, 1280, 1280, 1280, 1280, 0L, 0L);
        gemm_f32<0, 2, 2><<<dim3(20, 64, 1), 256, 0, stream>>>(
            h2, g3_w, g3_b, nullptr, out + img * 1280,
            4096, 1280, 1280, 1280, 1280, 0, 0L, 0L);
    }
}

// Round 3
// 1060.617 us; speedup vs baseline: 5.5897x; 5.5897x over previous
//
#include <hip/hip_runtime.h>
#include <hip/hip_bf16.h>

typedef __attribute__((ext_vector_type(8))) short short8;
typedef __attribute__((ext_vector_type(4))) float floatx4;
typedef unsigned short u16;

#define GLDS16(gp, lp) __builtin_amdgcn_global_load_lds(                        \
    (const __attribute__((address_space(1))) void*)(gp),                        \
    (__attribute__((address_space(3))) void*)(lp), 16, 0, 0)

__device__ inline u16 f2bf(float f) {
    unsigned u = __float_as_uint(f);
    unsigned r = (u + 0x7fffu + ((u >> 16) & 1u)) >> 16;
    return (u16)r;
}

// ---------------- block reduce (sum, sumsq) over 256 threads ----------------
__device__ inline void block_reduce2(float& s, float& ss) {
    #pragma unroll
    for (int o = 32; o > 0; o >>= 1) {
        s  += __shfl_down(s, o);
        ss += __shfl_down(ss, o);
    }
    __shared__ float red[8];
    const int t = threadIdx.x;
    if ((t & 63) == 0) { red[t >> 6] = s; red[4 + (t >> 6)] = ss; }
    __syncthreads();
    s  = red[0] + red[1] + red[2] + red[3];
    ss = red[4] + red[5] + red[6] + red[7];
}

// =============== bf16 MFMA GEMM, 128x128 tile, 4 waves, BK=32 (m97 structure) ===============
// C[M][N] = A(MxK) * B^T,  B stored [N][K] row-major bf16.
// AMODE: 0 = A row-major bf16 [M][K] (lda)
//        2 = im2col over zero-padded r_pad bf16 [512][81][1024]; k = tap*1024+ic, m = roi*49+sp
// EPI:   0 none, 1 +P1[n], 2 relu(x+P1[n]), 3 relu(x*P1[n]+P2[n])
// CMODE: 0 C f32 row-major(ldc), 1 conv-scatter bf16 C[roi][n*49+sp], 2 colsum atomic f32 (per 4096-row img),
//        3 atomicAdd f32 row-major(ldc) [split-K], 4 C bf16 row-major(ldc)
// Split-K: kbase = blockIdx.z * Kc; loop K range = [kbase, kbase+Kc)
template<int AMODE, int EPI, int CMODE>
__global__ __launch_bounds__(256)
void gemm_bf16(const u16* __restrict__ A, const u16* __restrict__ B,
               const float* __restrict__ P1, const float* __restrict__ P2,
               void* __restrict__ Cv,
               int M, int N, int Kc, int lda, int ldb, int ldc)
{
    __shared__ short As[128 * 32];
    __shared__ short Bs[128 * 32];

    const int t  = threadIdx.x;
    const int w  = t >> 6, l = t & 63;
    const int wr = w >> 1, wc = w & 1;
    const int l16 = l & 15, lr = l >> 4;
    const int m0 = blockIdx.y * 128, n0 = blockIdx.x * 128;
    const int kbase = blockIdx.z * Kc;

    // staging: issue it covers LDS bytes it*4096 + w*1024 + l*16
    // -> tile row = it*64 + w*16 + l/4, k-halfword offset = (l&3)*8
    const int srow  = w * 16 + (l >> 2);
    const int skoff = (l & 3) * 8;

    const u16* aRow0 = nullptr; const u16* aRow1 = nullptr;
    size_t aSp0 = 0, aSp1 = 0;
    if (AMODE == 0) {
        aRow0 = A + (size_t)(m0 + srow) * lda + kbase + skoff;
        aRow1 = A + (size_t)(m0 + 64 + srow) * lda + kbase + skoff;
    } else { // im2col: precompute spatial base (k-independent)
        const int r0 = m0 + srow, r1 = r0 + 64;
        const int roi0 = r0 / 49, sp0 = r0 - roi0 * 49;
        const int roi1 = r1 / 49, sp1 = r1 - roi1 * 49;
        aSp0 = ((size_t)roi0 * 81 + (sp0 / 7) * 9 + (sp0 % 7)) * 1024 + skoff;
        aSp1 = ((size_t)roi1 * 81 + (sp1 / 7) * 9 + (sp1 % 7)) * 1024 + skoff;
    }
    const u16* bRow0 = B + (size_t)(n0 + srow) * ldb + kbase + skoff;
    const u16* bRow1 = B + (size_t)(n0 + 64 + srow) * ldb + kbase + skoff;

    short* lA0 = As + w * 512;          // wave-uniform LDS bases (HW adds lane*16B)
    short* lA1 = As + 2048 + w * 512;
    short* lB0 = Bs + w * 512;
    short* lB1 = Bs + 2048 + w * 512;

    floatx4 acc[4][4] = {};

    for (int k0 = 0; k0 < Kc; k0 += 32) {
        if (AMODE == 0) {
            GLDS16(aRow0 + k0, lA0);
            GLDS16(aRow1 + k0, lA1);
        } else {
            const int kk  = kbase + k0;
            const int tap = kk >> 10;                       // uniform per k-step (32 | 1024)
            const size_t off = (size_t)((tap / 3) * 9 + (tap % 3)) * 1024 + (kk & 1023);
            GLDS16(A + aSp0 + off, lA0);
            GLDS16(A + aSp1 + off, lA1);
        }
        GLDS16(bRow0 + k0, lB0);
        GLDS16(bRow1 + k0, lB1);
        __syncthreads();   // drains vmcnt -> LDS tiles ready

        short8 af[4], bfr[4];
        #pragma unroll
        for (int i = 0; i < 4; ++i)
            af[i] = *reinterpret_cast<const short8*>(&As[(wr * 64 + i * 16 + l16) * 32 + lr * 8]);
        #pragma unroll
        for (int j = 0; j < 4; ++j)
            bfr[j] = *reinterpret_cast<const short8*>(&Bs[(wc * 64 + j * 16 + l16) * 32 + lr * 8]);
        #pragma unroll
        for (int i = 0; i < 4; ++i)
            #pragma unroll
            for (int j = 0; j < 4; ++j)
                acc[i][j] = __builtin_amdgcn_mfma_f32_16x16x32_bf16(af[i], bfr[j], acc[i][j], 0, 0, 0);
        __syncthreads();   // protect LDS from next iteration's staging
    }

    const int mBase = m0 + wr * 64;
    const int nBase = n0 + wc * 64;

    if (CMODE == 2) {   // fused column-sum (EPI==2 semantics), atomic into per-image out row
        __shared__ float red2[2][128];
        float csum[4];
        #pragma unroll
        for (int j = 0; j < 4; ++j) {
            const int n = nBase + j * 16 + l16;
            const float b1 = P1[n];
            float s = 0.f;
            #pragma unroll
            for (int i = 0; i < 4; ++i)
                #pragma unroll
                for (int r = 0; r < 4; ++r)
                    s += fmaxf(acc[i][j][r] + b1, 0.f);
            s += __shfl_xor(s, 16);
            s += __shfl_xor(s, 32);
            csum[j] = s;
        }
        if (l < 16) {
            #pragma unroll
            for (int j = 0; j < 4; ++j)
                red2[wr][wc * 64 + j * 16 + l16] = csum[j];
        }
        __syncthreads();
        float* C = (float*)Cv + (size_t)(m0 >> 12) * ldc;
        if (t < 128) atomicAdd(&C[n0 + t], red2[0][t] + red2[1][t]);
        return;
    }

    #pragma unroll
    for (int i = 0; i < 4; ++i) {
        #pragma unroll
        for (int j = 0; j < 4; ++j) {
            const int n = nBase + j * 16 + l16;
            const float b1 = (EPI >= 1) ? P1[n] : 0.f;
            const float b2 = (EPI == 3) ? P2[n] : 0.f;
            #pragma unroll
            for (int r = 0; r < 4; ++r) {
                float v = acc[i][j][r];
                if (EPI == 1)      v += b1;
                else if (EPI == 2) v = fmaxf(v + b1, 0.f);
                else if (EPI == 3) v = fmaxf(v * b1 + b2, 0.f);
                const int m = mBase + i * 16 + lr * 4 + r;
                if (CMODE == 0)      ((float*)Cv)[(size_t)m * ldc + n] = v;
                else if (CMODE == 4) ((u16*)Cv)[(size_t)m * ldc + n] = f2bf(v);
                else if (CMODE == 3) atomicAdd(&((float*)Cv)[(size_t)m * ldc + n], v);
                else if (CMODE == 1) {
                    const int roi = m / 49, sp = m - roi * 49;
                    ((u16*)Cv)[(size_t)roi * 12544 + n * 49 + sp] = f2bf(v);
                }
            }
        }
    }
}

// ---------------- im_feat [8][2048][256] f32 -> [8][256][2048] bf16 (LDS transpose) -------
__global__ __launch_bounds__(256)
void transpose_proj(const float* __restrict__ in, u16* __restrict__ out)
{
    __shared__ float tile[64][65];
    const int b = blockIdx.z;
    const int c0 = blockIdx.y * 64;    // channel tile
    const int h0 = blockIdx.x * 64;    // hw tile
    const int t = threadIdx.x;
    const float* src = in + ((size_t)b * 2048 + c0) * 256 + h0;
    #pragma unroll
    for (int p = 0; p < 16; ++p) {
        const int idx = p * 256 + t;
        const int r = idx >> 6, c = idx & 63;
        tile[r][c] = src[(size_t)r * 256 + c];
    }
    __syncthreads();
    u16* dst = out + ((size_t)b * 256 + h0) * 2048 + c0;
    #pragma unroll
    for (int p = 0; p < 16; ++p) {
        const int idx = p * 256 + t;
        const int r = idx >> 6, c = idx & 63;
        dst[(size_t)r * 2048 + c] = f2bf(tile[c][r]);
    }
}

// ---------------- zero the 1-pixel halo of r_pad [512][81][1024] bf16 ----------------
__global__ __launch_bounds__(256)
void zero_halo(u16* __restrict__ r_pad)
{
    const int blk = blockIdx.x;          // 512*32
    const int roi = blk >> 5, h = blk & 31;
    int p;
    if (h < 9)       p = h;                       // top row
    else if (h < 18) p = 72 + (h - 9);            // bottom row
    else { const int r = (h - 18) >> 1, s = (h - 18) & 1; p = (r + 1) * 9 + s * 8; }
    uint2* o = reinterpret_cast<uint2*>(r_pad + ((size_t)roi * 81 + p) * 1024);
    o[threadIdx.x] = make_uint2(0u, 0u);          // 256 * 8B = 1024 halfs
}

// ---------------- ROIAlignV2 (aligned=true), 2x2 samples/bin -> r_pad interior bf16 -------
__global__ __launch_bounds__(256)
void roialign_kernel(const float* __restrict__ x_cl, const float* __restrict__ boxes,
                     u16* __restrict__ r_pad)
{
    const int blk = blockIdx.x;          // n*49 + bin
    const int n = blk / 49, bin = blk % 49;
    const int py = bin / 7, px = bin % 7;
    const int b = n >> 6;
    const float* roi = boxes + n * 4;
    const float x1 = roi[0] * (1.f/32.f) - 0.5f;
    const float y1 = roi[1] * (1.f/32.f) - 0.5f;
    const float bw = (roi[2] - roi[0]) * (1.f/32.f) * (1.0f / 7.0f);
    const float bh = (roi[3] - roi[1]) * (1.f/32.f) * (1.0f / 7.0f);
    const int t = threadIdx.x;

    float acc[4] = {0.f, 0.f, 0.f, 0.f};
    #pragma unroll
    for (int sy = 0; sy < 2; ++sy) {
        #pragma unroll
        for (int sx = 0; sx < 2; ++sx) {
            const float yv = y1 + bh * ((float)(py * 2 + sy) + 0.5f) * 0.5f;
            const float xv = x1 + bw * ((float)(px * 2 + sx) + 0.5f) * 0.5f;
            const bool vy = (yv >= -1.0f) && (yv <= 16.0f);
            const bool vx = (xv >= -1.0f) && (xv <= 16.0f);
            if (!(vy && vx)) continue;
            float yc = fmaxf(yv, 0.f);
            int yl = (int)floorf(yc);
            int yh; if (yl >= 15) { yl = 15; yc = 15.f; yh = 15; } else yh = yl + 1;
            const float wy = yc - (float)yl;
            float xc = fmaxf(xv, 0.f);
            int xl = (int)floorf(xc);
            int xh; if (xl >= 15) { xl = 15; xc = 15.f; xh = 15; } else xh = xl + 1;
            const float wx = xc - (float)xl;

            const float w00 = (1.f - wy) * (1.f - wx), w01 = (1.f - wy) * wx;
            const float w10 = wy * (1.f - wx),         w11 = wy * wx;
            const float* p00 = x_cl + ((size_t)b * 256 + yl * 16 + xl) * 1024;
            const float* p01 = x_cl + ((size_t)b * 256 + yl * 16 + xh) * 1024;
            const float* p10 = x_cl + ((size_t)b * 256 + yh * 16 + xl) * 1024;
            const float* p11 = x_cl + ((size_t)b * 256 + yh * 16 + xh) * 1024;
            #pragma unroll
            for (int cc = 0; cc < 4; ++cc) {
                const int c = t + cc * 256;
                acc[cc] += w00 * p00[c] + w01 * p01[c] + w10 * p10[c] + w11 * p11[c];
            }
        }
    }
    u16* o = r_pad + ((size_t)n * 81 + (py + 1) * 9 + (px + 1)) * 1024;
    #pragma unroll
    for (int cc = 0; cc < 4; ++cc) o[t + cc * 256] = f2bf(acc[cc] * 0.25f);
}

// ---------------- conv weight pack (tap-major K) bf16 + BN fold ----------------
__global__ __launch_bounds__(256)
void pack_conv(const float* __restrict__ conv_w, const float* __restrict__ conv_b,
               const float* __restrict__ bn_g, const float* __restrict__ bn_b,
               const float* __restrict__ bn_m, const float* __restrict__ bn_v,
               u16* __restrict__ wpack, float* __restrict__ scale, float* __restrict__ shift)
{
    const long idx = (long)blockIdx.x * 256 + threadIdx.x;
    if (idx < 2359296L) {
        const int oc = (int)(idx / 9216), k = (int)(idx % 9216);
        const int tap = k >> 10, ic = k & 1023;
        wpack[idx] = f2bf(conv_w[(long)oc * 9216 + ic * 9 + tap]);
    }
    if (idx < 256) {
        const float s = bn_g[idx] * rsqrtf(bn_v[idx] + 1e-5f);
        scale[idx] = s;
        shift[idx] = (conv_b[idx] - bn_m[idx]) * s + bn_b[idx];
    }
}

// ---------------- straight f32 -> bf16 convert (xN/4) ----------------
__global__ __launch_bounds__(256)
void cvt_bf16(const float* __restrict__ in, u16* __restrict__ out, int n4)
{
    const int i = blockIdx.x * 256 + threadIdx.x;
    if (i < n4) {
        const float4 v = reinterpret_cast<const float4*>(in)[i];
        ushort4 o; o.x = f2bf(v.x); o.y = f2bf(v.y); o.z = f2bf(v.z); o.w = f2bf(v.w);
        reinterpret_cast<ushort4*>(out)[i] = o;
    }
}

// ---------------- g1_w [1280][2560] f32 -> [2560][1280] bf16 (U rows then V rows) ----------
__global__ __launch_bounds__(256)
void pack_g1(const float* __restrict__ g1w, u16* __restrict__ out)
{
    const int j = blockIdx.x * 256 + threadIdx.x;   // 2560 * 320
    if (j >= 2560 * 320) return;
    const int np = j / 320, k4 = (j - np * 320) * 4;
    const int srow = (np < 1280) ? np : np - 1280;
    const int soff = (np < 1280) ? 0 : 1280;
    const float4 v = *reinterpret_cast<const float4*>(&g1w[(size_t)srow * 2560 + soff + k4]);
    ushort4 o; o.x = f2bf(v.x); o.y = f2bf(v.y); o.z = f2bf(v.z); o.w = f2bf(v.w);
    *reinterpret_cast<ushort4*>(&out[(size_t)np * 1280 + k4]) = o;
}

// ---------------- fc bias + relu + LayerNorm(1024) -> feats[:, :1024] bf16 ----------------
__global__ __launch_bounds__(256)
void ln1_kernel(const float* __restrict__ in, const float* __restrict__ fb,
                const float* __restrict__ g, const float* __restrict__ b,
                u16* __restrict__ feats)
{
    const int n = blockIdx.x, t = threadIdx.x;
    float4 v = *reinterpret_cast<const float4*>(in + (size_t)n * 1024 + t * 4);
    const float4 bb = *reinterpret_cast<const float4*>(fb + t * 4);
    v.x = fmaxf(v.x + bb.x, 0.f); v.y = fmaxf(v.y + bb.y, 0.f);
    v.z = fmaxf(v.z + bb.z, 0.f); v.w = fmaxf(v.w + bb.w, 0.f);
    float s  = v.x + v.y + v.z + v.w;
    float ss = v.x*v.x + v.y*v.y + v.z*v.z + v.w*v.w;
    block_reduce2(s, ss);
    const float mu  = s * (1.f / 1024.f);
    const float var = ss * (1.f / 1024.f) - mu * mu;
    const float r   = rsqrtf(var + 1e-5f);
    const float4 gp = *reinterpret_cast<const float4*>(g + t * 4);
    const float4 bp = *reinterpret_cast<const float4*>(b + t * 4);
    ushort4 o;
    o.x = f2bf((v.x - mu) * r * gp.x + bp.x);
    o.y = f2bf((v.y - mu) * r * gp.y + bp.y);
    o.z = f2bf((v.z - mu) * r * gp.z + bp.z);
    o.w = f2bf((v.w - mu) * r * gp.w + bp.w);
    *reinterpret_cast<ushort4*>(feats + (size_t)n * 1280 + t * 4) = o;
}

// ---------------- box branch -> feats[:, 1024:1280] bf16 ----------------
__global__ __launch_bounds__(256)
void box_kernel(const float* __restrict__ nb, const float* __restrict__ bw,
                const float* __restrict__ bb, const float* __restrict__ g,
                const float* __restrict__ be, u16* __restrict__ feats)
{
    const int n = blockIdx.x, j = threadIdx.x;
    const float4 q = *reinterpret_cast<const float4*>(nb + n * 4);
    const float4 w = *reinterpret_cast<const float4*>(bw + j * 4);
    const float v = (q.x * 2.f - 1.f) * w.x + (q.y * 2.f - 1.f) * w.y
                  + (q.z * 2.f - 1.f) * w.z + (q.w * 2.f - 1.f) * w.w + bb[j];
    float s = v, ss = v * v;
    block_reduce2(s, ss);
    const float mu  = s * (1.f / 256.f);
    const float var = ss * (1.f / 256.f) - mu * mu;
    feats[(size_t)n * 1280 + 1024 + j] = f2bf((v - mu) * rsqrtf(var + 1e-5f) * g[j] + be[j]);
}

// ---------------- pair expansion (4-image chunk): h1 = relu(U[b]+V[a]+g1_b) bf16 ----------
__global__ __launch_bounds__(256)
void pair_kernel(const float* __restrict__ UV, const float* __restrict__ g1b,
                 u16* __restrict__ h1, int imgbase)
{
    const int pidx = blockIdx.y;                       // 0..16383
    const int img = imgbase + (pidx >> 12);
    const int a = (pidx >> 6) & 63, b = pidx & 63;
    const int col = blockIdx.x * 256 + threadIdx.x;    // grid.x = 5
    const float v = UV[(size_t)(img * 64 + b) * 2560 + col]
                  + UV[(size_t)(img * 64 + a) * 2560 + 1280 + col] + g1b[col];
    h1[(size_t)pidx * 1280 + col] = f2bf(fmaxf(v, 0.f));
}

__global__ void zero_f32(float* __restrict__ p, int n) {
    const int i = blockIdx.x * 256 + threadIdx.x;
    if (i < n) p[i] = 0.f;
}

// =======================================================================================
extern "C" void kernel_launch(void* const* d_in, const int* in_sizes, int n_in,
                              void* d_out, int out_size, void* d_ws, size_t ws_size,
                              hipStream_t stream)
{
    const float* im_feat = (const float*)d_in[0];
    const float* boxes   = (const float*)d_in[1];
    const float* nboxes  = (const float*)d_in[2];
    const float* proj_w  = (const float*)d_in[3];
    const float* proj_b  = (const float*)d_in[4];
    const float* conv_w  = (const float*)d_in[5];
    const float* conv_b  = (const float*)d_in[6];
    const float* bn_g    = (const float*)d_in[7];
    const float* bn_b    = (const float*)d_in[8];
    const float* bn_m    = (const float*)d_in[9];
    const float* bn_v    = (const float*)d_in[10];
    const float* fc_w    = (const float*)d_in[11];
    const float* fc_b    = (const float*)d_in[12];
    const float* ln1_g   = (const float*)d_in[13];
    const float* ln1_b   = (const float*)d_in[14];
    const float* box_w   = (const float*)d_in[15];
    const float* box_b   = (const float*)d_in[16];
    const float* ln2_g   = (const float*)d_in[17];
    const float* ln2_b   = (const float*)d_in[18];
    const float* g1_w    = (const float*)d_in[19];
    const float* g1_b    = (const float*)d_in[20];
    const float* g2_w    = (const float*)d_in[21];
    const float* g2_b    = (const float*)d_in[22];
    const float* g3_w    = (const float*)d_in[23];
    const float* g3_b    = (const float*)d_in[24];
    float* out = (float*)d_out;
    (void)in_sizes; (void)n_in; (void)out_size; (void)ws_size;

    // -------- workspace carve (bytes, 16B aligned); total ~171 MB --------
    char* base = (char*)d_ws;
    size_t o = 0;
    auto carve = [&](size_t bytes) { char* p = base + o; o += (bytes + 15) & ~(size_t)15; return p; };
    float* x_cl    = (float*)carve(8388608);      // [2048][1024] f32 (proj out, channels-last)
    u16*   imT     = (u16*)  carve(8388608);      // [8*256][2048] bf16
    u16*   convout = (u16*)  carve(12845056);     // [512][12544] bf16
    float* fc_out  = (float*)carve(2097152);      // [512][1024] f32 (atomic acc)
    u16*   feats   = (u16*)  carve(1310720);      // [512][1280] bf16
    float* UV      = (float*)carve(5242880);      // [512][2560] f32 (atomic acc)
    u16*   wpack   = (u16*)  carve(4718592);      // [256][9216] bf16
    float* scale   = (float*)carve(1024);
    float* shift   = (float*)carve(1024);
    u16*   projwb  = (u16*)  carve(4194304);      // [1024][2048] bf16
    u16*   fcwb    = (u16*)  carve(25690112);     // [1024][12544] bf16
    u16*   g1wb    = (u16*)  carve(6553600);      // [2560][1280] bf16
    u16*   g2wb    = (u16*)  carve(3276800);      // [1280][1280] bf16
    u16*   g3wb    = (u16*)  carve(3276800);      // [1280][1280] bf16
    char*  big     = carve(84934656);             // r_pad [512][81][1024] bf16; later h1+h2
    u16*   r_pad   = (u16*)big;
    u16*   h1      = (u16*)big;                   // [16384][1280] bf16 (after conv GEMM done)
    u16*   h2      = (u16*)(big + 41943040);      // [16384][1280] bf16

    // -------- zero accumulators --------
    zero_f32<<<40, 256, 0, stream>>>(out, 10240);
    zero_f32<<<2048, 256, 0, stream>>>(fc_out, 524288);
    zero_f32<<<5120, 256, 0, stream>>>(UV, 1310720);

    // -------- weight conversion / packing --------
    cvt_bf16<<<2048, 256, 0, stream>>>(proj_w, projwb, 524288);
    cvt_bf16<<<12544, 256, 0, stream>>>(fc_w, fcwb, 3211264);
    cvt_bf16<<<1600, 256, 0, stream>>>(g2_w, g2wb, 409600);
    cvt_bf16<<<1600, 256, 0, stream>>>(g3_w, g3wb, 409600);
    pack_g1<<<3200, 256, 0, stream>>>(g1_w, g1wb);
    pack_conv<<<9216, 256, 0, stream>>>(conv_w, conv_b, bn_g, bn_b, bn_m, bn_v, wpack, scale, shift);

    // -------- 1x1 projection: transpose to bf16 then MFMA GEMM --------
    transpose_proj<<<dim3(4, 32, 8), 256, 0, stream>>>(im_feat, imT);
    gemm_bf16<0, 1, 0><<<dim3(8, 16, 1), 256, 0, stream>>>(
        imT, projwb, proj_b, nullptr, x_cl, 2048, 1024, 2048, 2048, 2048, 1024);

    // -------- ROIAlign into zero-padded bf16 buffer --------
    zero_halo<<<16384, 256, 0, stream>>>(r_pad);
    roialign_kernel<<<25088, 256, 0, stream>>>(x_cl, boxes, r_pad);

    // -------- conv3x3 + BN + ReLU (im2col MFMA), scatter to [roi][oc*49+sp] bf16 --------
    gemm_bf16<2, 3, 1><<<dim3(2, 196, 1), 256, 0, stream>>>(
        r_pad, wpack, scale, shift, convout, 25088, 256, 9216, 0, 9216, 0);

    // -------- FC (split-K 4, atomic f32): raw sum; bias+relu fused into LN1 --------
    gemm_bf16<0, 0, 3><<<dim3(8, 4, 4), 256, 0, stream>>>(
        convout, fcwb, nullptr, nullptr, fc_out, 512, 1024, 3136, 12544, 12544, 1024);

    ln1_kernel<<<512, 256, 0, stream>>>(fc_out, fc_b, ln1_g, ln1_b, feats);
    box_kernel<<<512, 256, 0, stream>>>(nboxes, box_w, box_b, ln2_g, ln2_b, feats);

    // -------- U/V GEMM (split-K 2, atomic f32): UV[m][n<1280]=U, UV[m][1280+n]=V --------
    gemm_bf16<0, 0, 3><<<dim3(20, 4, 2), 256, 0, stream>>>(
        feats, g1wb, nullptr, nullptr, UV, 512, 2560, 640, 1280, 1280, 2560);

    // -------- relation: 2 chunks of 4 images --------
    for (int h = 0; h < 2; ++h) {
        pair_kernel<<<dim3(5, 16384), 256, 0, stream>>>(UV, g1_b, h1, h * 4);
        gemm_bf16<0, 2, 4><<<dim3(10, 128, 1), 256, 0, stream>>>(
            h1, g2wb, g2_b, nullptr, h2, 16384, 1280, 1280, 1280, 1280, 1280);
        gemm_bf16<0, 2, 2><<<dim3(10, 128, 1), 256, 0, stream>>>(
            h2, g3wb, g3_b, nullptr, out + h * 4 * 1280, 16384, 1280, 1280, 1280, 1280, 1280);
    }
}

// Round 4
// 1020.035 us; speedup vs baseline: 5.8121x; 1.0398x over previous
//
#include <hip/hip_runtime.h>
#include <hip/hip_bf16.h>

typedef __attribute__((ext_vector_type(8))) short short8;
typedef __attribute__((ext_vector_type(4))) float floatx4;
typedef unsigned short u16;

#define GLDS16(gp, lp) __builtin_amdgcn_global_load_lds(                        \
    (const __attribute__((address_space(1))) void*)(gp),                        \
    (__attribute__((address_space(3))) void*)(lp), 16, 0, 0)

__device__ inline u16 f2bf(float f) {
    unsigned u = __float_as_uint(f);
    unsigned r = (u + 0x7fffu + ((u >> 16) & 1u)) >> 16;
    return (u16)r;
}

// ---------------- block reduce (sum, sumsq) over 256 threads ----------------
__device__ inline void block_reduce2(float& s, float& ss) {
    #pragma unroll
    for (int o = 32; o > 0; o >>= 1) {
        s  += __shfl_down(s, o);
        ss += __shfl_down(ss, o);
    }
    __shared__ float red[8];
    const int t = threadIdx.x;
    if ((t & 63) == 0) { red[t >> 6] = s; red[4 + (t >> 6)] = ss; }
    __syncthreads();
    s  = red[0] + red[1] + red[2] + red[3];
    ss = red[4] + red[5] + red[6] + red[7];
}

// =============== bf16 MFMA GEMM, 128x128 tile, 4 waves, BK=32 (m97 structure) ===============
// C[M][N] = A(MxK) * B^T,  B stored [N][K] row-major bf16.
// T1: XCD-aware bijective block swizzle (requires gridDim.x*gridDim.y % 8 == 0):
//     consecutive swizzled ids share one m-tile across n (A-panel L2 reuse per XCD).
// AMODE: 0 = A row-major bf16 [M][K] (lda)
//        2 = im2col over zero-padded r_pad bf16 [512][81][1024]; k = tap*1024+ic, m = roi*49+sp
// EPI:   0 none, 1 +P1[n], 2 relu(x+P1[n]), 3 relu(x*P1[n]+P2[n])
// CMODE: 0 C f32 row-major(ldc), 1 conv-scatter bf16 C[roi][n*49+sp], 2 colsum atomic f32 (per 4096-row img),
//        3 atomicAdd f32 row-major(ldc) [split-K], 4 C bf16 row-major(ldc)
// Split-K: kbase = blockIdx.z * Kc; loop K range = [kbase, kbase+Kc)
template<int AMODE, int EPI, int CMODE>
__global__ __launch_bounds__(256)
void gemm_bf16(const u16* __restrict__ A, const u16* __restrict__ B,
               const float* __restrict__ P1, const float* __restrict__ P2,
               void* __restrict__ Cv,
               int M, int N, int Kc, int lda, int ldb, int ldc)
{
    __shared__ short As[128 * 32];
    __shared__ short Bs[128 * 32];

    const int t  = threadIdx.x;
    const int w  = t >> 6, l = t & 63;
    const int wr = w >> 1, wc = w & 1;
    const int l16 = l & 15, lr = l >> 4;

    // ---- T1 XCD swizzle: bid -> (xcd = bid%8) gets contiguous chunk of tile space ----
    const int nwg = gridDim.x * gridDim.y;
    const int bid = blockIdx.y * gridDim.x + blockIdx.x;
    const int cpx = nwg >> 3;                       // nwg % 8 == 0 for all call sites
    const int sw  = (bid & 7) * cpx + (bid >> 3);
    const int n0 = (sw % gridDim.x) * 128;          // n fastest within an XCD chunk
    const int m0 = (sw / gridDim.x) * 128;
    const int kbase = blockIdx.z * Kc;

    // staging: issue it covers LDS bytes it*4096 + w*1024 + l*16
    // -> tile row = it*64 + w*16 + l/4, k-halfword offset = (l&3)*8
    const int srow  = w * 16 + (l >> 2);
    const int skoff = (l & 3) * 8;

    const u16* aRow0 = nullptr; const u16* aRow1 = nullptr;
    size_t aSp0 = 0, aSp1 = 0;
    if (AMODE == 0) {
        aRow0 = A + (size_t)(m0 + srow) * lda + kbase + skoff;
        aRow1 = A + (size_t)(m0 + 64 + srow) * lda + kbase + skoff;
    } else { // im2col: precompute spatial base (k-independent)
        const int r0 = m0 + srow, r1 = r0 + 64;
        const int roi0 = r0 / 49, sp0 = r0 - roi0 * 49;
        const int roi1 = r1 / 49, sp1 = r1 - roi1 * 49;
        aSp0 = ((size_t)roi0 * 81 + (sp0 / 7) * 9 + (sp0 % 7)) * 1024 + skoff;
        aSp1 = ((size_t)roi1 * 81 + (sp1 / 7) * 9 + (sp1 % 7)) * 1024 + skoff;
    }
    const u16* bRow0 = B + (size_t)(n0 + srow) * ldb + kbase + skoff;
    const u16* bRow1 = B + (size_t)(n0 + 64 + srow) * ldb + kbase + skoff;

    short* lA0 = As + w * 512;          // wave-uniform LDS bases (HW adds lane*16B)
    short* lA1 = As + 2048 + w * 512;
    short* lB0 = Bs + w * 512;
    short* lB1 = Bs + 2048 + w * 512;

    floatx4 acc[4][4] = {};

    for (int k0 = 0; k0 < Kc; k0 += 32) {
        if (AMODE == 0) {
            GLDS16(aRow0 + k0, lA0);
            GLDS16(aRow1 + k0, lA1);
        } else {
            const int kk  = kbase + k0;
            const int tap = kk >> 10;                       // uniform per k-step (32 | 1024)
            const size_t off = (size_t)((tap / 3) * 9 + (tap % 3)) * 1024 + (kk & 1023);
            GLDS16(A + aSp0 + off, lA0);
            GLDS16(A + aSp1 + off, lA1);
        }
        GLDS16(bRow0 + k0, lB0);
        GLDS16(bRow1 + k0, lB1);
        __syncthreads();   // drains vmcnt -> LDS tiles ready

        short8 af[4], bfr[4];
        #pragma unroll
        for (int i = 0; i < 4; ++i)
            af[i] = *reinterpret_cast<const short8*>(&As[(wr * 64 + i * 16 + l16) * 32 + lr * 8]);
        #pragma unroll
        for (int j = 0; j < 4; ++j)
            bfr[j] = *reinterpret_cast<const short8*>(&Bs[(wc * 64 + j * 16 + l16) * 32 + lr * 8]);
        #pragma unroll
        for (int i = 0; i < 4; ++i)
            #pragma unroll
            for (int j = 0; j < 4; ++j)
                acc[i][j] = __builtin_amdgcn_mfma_f32_16x16x32_bf16(af[i], bfr[j], acc[i][j], 0, 0, 0);
        __syncthreads();   // protect LDS from next iteration's staging
    }

    const int mBase = m0 + wr * 64;
    const int nBase = n0 + wc * 64;

    if (CMODE == 2) {   // fused column-sum (EPI==2 semantics), atomic into per-image out row
        __shared__ float red2[2][128];
        float csum[4];
        #pragma unroll
        for (int j = 0; j < 4; ++j) {
            const int n = nBase + j * 16 + l16;
            const float b1 = P1[n];
            float s = 0.f;
            #pragma unroll
            for (int i = 0; i < 4; ++i)
                #pragma unroll
                for (int r = 0; r < 4; ++r)
                    s += fmaxf(acc[i][j][r] + b1, 0.f);
            s += __shfl_xor(s, 16);
            s += __shfl_xor(s, 32);
            csum[j] = s;
        }
        if (l < 16) {
            #pragma unroll
            for (int j = 0; j < 4; ++j)
                red2[wr][wc * 64 + j * 16 + l16] = csum[j];
        }
        __syncthreads();
        float* C = (float*)Cv + (size_t)(m0 >> 12) * ldc;
        if (t < 128) atomicAdd(&C[n0 + t], red2[0][t] + red2[1][t]);
        return;
    }

    #pragma unroll
    for (int i = 0; i < 4; ++i) {
        #pragma unroll
        for (int j = 0; j < 4; ++j) {
            const int n = nBase + j * 16 + l16;
            const float b1 = (EPI >= 1) ? P1[n] : 0.f;
            const float b2 = (EPI == 3) ? P2[n] : 0.f;
            #pragma unroll
            for (int r = 0; r < 4; ++r) {
                float v = acc[i][j][r];
                if (EPI == 1)      v += b1;
                else if (EPI == 2) v = fmaxf(v + b1, 0.f);
                else if (EPI == 3) v = fmaxf(v * b1 + b2, 0.f);
                const int m = mBase + i * 16 + lr * 4 + r;
                if (CMODE == 0)      ((float*)Cv)[(size_t)m * ldc + n] = v;
                else if (CMODE == 4) ((u16*)Cv)[(size_t)m * ldc + n] = f2bf(v);
                else if (CMODE == 3) atomicAdd(&((float*)Cv)[(size_t)m * ldc + n], v);
                else if (CMODE == 1) {
                    const int roi = m / 49, sp = m - roi * 49;
                    ((u16*)Cv)[(size_t)roi * 12544 + n * 49 + sp] = f2bf(v);
                }
            }
        }
    }
}

// ---------------- im_feat [8][2048][256] f32 -> [8][256][2048] bf16 (LDS transpose) -------
__global__ __launch_bounds__(256)
void transpose_proj(const float* __restrict__ in, u16* __restrict__ out)
{
    __shared__ float tile[64][65];
    const int b = blockIdx.z;
    const int c0 = blockIdx.y * 64;    // channel tile
    const int h0 = blockIdx.x * 64;    // hw tile
    const int t = threadIdx.x;
    const float* src = in + ((size_t)b * 2048 + c0) * 256 + h0;
    #pragma unroll
    for (int p = 0; p < 16; ++p) {
        const int idx = p * 256 + t;
        const int r = idx >> 6, c = idx & 63;
        tile[r][c] = src[(size_t)r * 256 + c];
    }
    __syncthreads();
    u16* dst = out + ((size_t)b * 256 + h0) * 2048 + c0;
    #pragma unroll
    for (int p = 0; p < 16; ++p) {
        const int idx = p * 256 + t;
        const int r = idx >> 6, c = idx & 63;
        dst[(size_t)r * 2048 + c] = f2bf(tile[c][r]);
    }
}

// ---------------- zero the 1-pixel halo of r_pad [512][81][1024] bf16 ----------------
__global__ __launch_bounds__(256)
void zero_halo(u16* __restrict__ r_pad)
{
    const int blk = blockIdx.x;          // 512*32
    const int roi = blk >> 5, h = blk & 31;
    int p;
    if (h < 9)       p = h;                       // top row
    else if (h < 18) p = 72 + (h - 9);            // bottom row
    else { const int r = (h - 18) >> 1, s = (h - 18) & 1; p = (r + 1) * 9 + s * 8; }
    uint2* o = reinterpret_cast<uint2*>(r_pad + ((size_t)roi * 81 + p) * 1024);
    o[threadIdx.x] = make_uint2(0u, 0u);          // 256 * 8B = 1024 halfs
}

// ---------------- ROIAlignV2 (aligned=true), 2x2 samples/bin -> r_pad interior bf16 -------
__global__ __launch_bounds__(256)
void roialign_kernel(const float* __restrict__ x_cl, const float* __restrict__ boxes,
                     u16* __restrict__ r_pad)
{
    const int blk = blockIdx.x;          // n*49 + bin
    const int n = blk / 49, bin = blk % 49;
    const int py = bin / 7, px = bin % 7;
    const int b = n >> 6;
    const float* roi = boxes + n * 4;
    const float x1 = roi[0] * (1.f/32.f) - 0.5f;
    const float y1 = roi[1] * (1.f/32.f) - 0.5f;
    const float bw = (roi[2] - roi[0]) * (1.f/32.f) * (1.0f / 7.0f);
    const float bh = (roi[3] - roi[1]) * (1.f/32.f) * (1.0f / 7.0f);
    const int t = threadIdx.x;

    float acc[4] = {0.f, 0.f, 0.f, 0.f};
    #pragma unroll
    for (int sy = 0; sy < 2; ++sy) {
        #pragma unroll
        for (int sx = 0; sx < 2; ++sx) {
            const float yv = y1 + bh * ((float)(py * 2 + sy) + 0.5f) * 0.5f;
            const float xv = x1 + bw * ((float)(px * 2 + sx) + 0.5f) * 0.5f;
            const bool vy = (yv >= -1.0f) && (yv <= 16.0f);
            const bool vx = (xv >= -1.0f) && (xv <= 16.0f);
            if (!(vy && vx)) continue;
            float yc = fmaxf(yv, 0.f);
            int yl = (int)floorf(yc);
            int yh; if (yl >= 15) { yl = 15; yc = 15.f; yh = 15; } else yh = yl + 1;
            const float wy = yc - (float)yl;
            float xc = fmaxf(xv, 0.f);
            int xl = (int)floorf(xc);
            int xh; if (xl >= 15) { xl = 15; xc = 15.f; xh = 15; } else xh = xl + 1;
            const float wx = xc - (float)xl;

            const float w00 = (1.f - wy) * (1.f - wx), w01 = (1.f - wy) * wx;
            const float w10 = wy * (1.f - wx),         w11 = wy * wx;
            const float* p00 = x_cl + ((size_t)b * 256 + yl * 16 + xl) * 1024;
            const float* p01 = x_cl + ((size_t)b * 256 + yl * 16 + xh) * 1024;
            const float* p10 = x_cl + ((size_t)b * 256 + yh * 16 + xl) * 1024;
            const float* p11 = x_cl + ((size_t)b * 256 + yh * 16 + xh) * 1024;
            #pragma unroll
            for (int cc = 0; cc < 4; ++cc) {
                const int c = t + cc * 256;
                acc[cc] += w00 * p00[c] + w01 * p01[c] + w10 * p10[c] + w11 * p11[c];
            }
        }
    }
    u16* o = r_pad + ((size_t)n * 81 + (py + 1) * 9 + (px + 1)) * 1024;
    #pragma unroll
    for (int cc = 0; cc < 4; ++cc) o[t + cc * 256] = f2bf(acc[cc] * 0.25f);
}

// ---------------- conv weight pack (tap-major K) bf16 + BN fold ----------------
__global__ __launch_bounds__(256)
void pack_conv(const float* __restrict__ conv_w, const float* __restrict__ conv_b,
               const float* __restrict__ bn_g, const float* __restrict__ bn_b,
               const float* __restrict__ bn_m, const float* __restrict__ bn_v,
               u16* __restrict__ wpack, float* __restrict__ scale, float* __restrict__ shift)
{
    const long idx = (long)blockIdx.x * 256 + threadIdx.x;
    if (idx < 2359296L) {
        const int oc = (int)(idx / 9216), k = (int)(idx % 9216);
        const int tap = k >> 10, ic = k & 1023;
        wpack[idx] = f2bf(conv_w[(long)oc * 9216 + ic * 9 + tap]);
    }
    if (idx < 256) {
        const float s = bn_g[idx] * rsqrtf(bn_v[idx] + 1e-5f);
        scale[idx] = s;
        shift[idx] = (conv_b[idx] - bn_m[idx]) * s + bn_b[idx];
    }
}

// ---------------- straight f32 -> bf16 convert (xN/4) ----------------
__global__ __launch_bounds__(256)
void cvt_bf16(const float* __restrict__ in, u16* __restrict__ out, int n4)
{
    const int i = blockIdx.x * 256 + threadIdx.x;
    if (i < n4) {
        const float4 v = reinterpret_cast<const float4*>(in)[i];
        ushort4 o; o.x = f2bf(v.x); o.y = f2bf(v.y); o.z = f2bf(v.z); o.w = f2bf(v.w);
        reinterpret_cast<ushort4*>(out)[i] = o;
    }
}

// ---------------- g1_w [1280][2560] f32 -> [2560][1280] bf16 (U rows then V rows) ----------
__global__ __launch_bounds__(256)
void pack_g1(const float* __restrict__ g1w, u16* __restrict__ out)
{
    const int j = blockIdx.x * 256 + threadIdx.x;   // 2560 * 320
    if (j >= 2560 * 320) return;
    const int np = j / 320, k4 = (j - np * 320) * 4;
    const int srow = (np < 1280) ? np : np - 1280;
    const int soff = (np < 1280) ? 0 : 1280;
    const float4 v = *reinterpret_cast<const float4*>(&g1w[(size_t)srow * 2560 + soff + k4]);
    ushort4 o; o.x = f2bf(v.x); o.y = f2bf(v.y); o.z = f2bf(v.z); o.w = f2bf(v.w);
    *reinterpret_cast<ushort4*>(&out[(size_t)np * 1280 + k4]) = o;
}

// ---------------- fc bias + relu + LayerNorm(1024) -> feats[:, :1024] bf16 ----------------
__global__ __launch_bounds__(256)
void ln1_kernel(const float* __restrict__ in, const float* __restrict__ fb,
                const float* __restrict__ g, const float* __restrict__ b,
                u16* __restrict__ feats)
{
    const int n = blockIdx.x, t = threadIdx.x;
    float4 v = *reinterpret_cast<const float4*>(in + (size_t)n * 1024 + t * 4);
    const float4 bb = *reinterpret_cast<const float4*>(fb + t * 4);
    v.x = fmaxf(v.x + bb.x, 0.f); v.y = fmaxf(v.y + bb.y, 0.f);
    v.z = fmaxf(v.z + bb.z, 0.f); v.w = fmaxf(v.w + bb.w, 0.f);
    float s  = v.x + v.y + v.z + v.w;
    float ss = v.x*v.x + v.y*v.y + v.z*v.z + v.w*v.w;
    block_reduce2(s, ss);
    const float mu  = s * (1.f / 1024.f);
    const float var = ss * (1.f / 1024.f) - mu * mu;
    const float r   = rsqrtf(var + 1e-5f);
    const float4 gp = *reinterpret_cast<const float4*>(g + t * 4);
    const float4 bp = *reinterpret_cast<const float4*>(b + t * 4);
    ushort4 o;
    o.x = f2bf((v.x - mu) * r * gp.x + bp.x);
    o.y = f2bf((v.y - mu) * r * gp.y + bp.y);
    o.z = f2bf((v.z - mu) * r * gp.z + bp.z);
    o.w = f2bf((v.w - mu) * r * gp.w + bp.w);
    *reinterpret_cast<ushort4*>(feats + (size_t)n * 1280 + t * 4) = o;
}

// ---------------- box branch -> feats[:, 1024:1280] bf16 ----------------
__global__ __launch_bounds__(256)
void box_kernel(const float* __restrict__ nb, const float* __restrict__ bw,
                const float* __restrict__ bb, const float* __restrict__ g,
                const float* __restrict__ be, u16* __restrict__ feats)
{
    const int n = blockIdx.x, j = threadIdx.x;
    const float4 q = *reinterpret_cast<const float4*>(nb + n * 4);
    const float4 w = *reinterpret_cast<const float4*>(bw + j * 4);
    const float v = (q.x * 2.f - 1.f) * w.x + (q.y * 2.f - 1.f) * w.y
                  + (q.z * 2.f - 1.f) * w.z + (q.w * 2.f - 1.f) * w.w + bb[j];
    float s = v, ss = v * v;
    block_reduce2(s, ss);
    const float mu  = s * (1.f / 256.f);
    const float var = ss * (1.f / 256.f) - mu * mu;
    feats[(size_t)n * 1280 + 1024 + j] = f2bf((v - mu) * rsqrtf(var + 1e-5f) * g[j] + be[j]);
}

// ---------------- pair expansion (4-image chunk): h1 = relu(U[b]+V[a]+g1_b) bf16 ----------
__global__ __launch_bounds__(256)
void pair_kernel(const float* __restrict__ UV, const float* __restrict__ g1b,
                 u16* __restrict__ h1, int imgbase)
{
    const int pidx = blockIdx.y;                       // 0..16383
    const int img = imgbase + (pidx >> 12);
    const int a = (pidx >> 6) & 63, b = pidx & 63;
    const int col = blockIdx.x * 256 + threadIdx.x;    // grid.x = 5
    const float v = UV[(size_t)(img * 64 + b) * 2560 + col]
                  + UV[(size_t)(img * 64 + a) * 2560 + 1280 + col] + g1b[col];
    h1[(size_t)pidx * 1280 + col] = f2bf(fmaxf(v, 0.f));
}

__global__ void zero_f32(float* __restrict__ p, int n) {
    const int i = blockIdx.x * 256 + threadIdx.x;
    if (i < n) p[i] = 0.f;
}

// =======================================================================================
extern "C" void kernel_launch(void* const* d_in, const int* in_sizes, int n_in,
                              void* d_out, int out_size, void* d_ws, size_t ws_size,
                              hipStream_t stream)
{
    const float* im_feat = (const float*)d_in[0];
    const float* boxes   = (const float*)d_in[1];
    const float* nboxes  = (const float*)d_in[2];
    const float* proj_w  = (const float*)d_in[3];
    const float* proj_b  = (const float*)d_in[4];
    const float* conv_w  = (const float*)d_in[5];
    const float* conv_b  = (const float*)d_in[6];
    const float* bn_g    = (const float*)d_in[7];
    const float* bn_b    = (const float*)d_in[8];
    const float* bn_m    = (const float*)d_in[9];
    const float* bn_v    = (const float*)d_in[10];
    const float* fc_w    = (const float*)d_in[11];
    const float* fc_b    = (const float*)d_in[12];
    const float* ln1_g   = (const float*)d_in[13];
    const float* ln1_b   = (const float*)d_in[14];
    const float* box_w   = (const float*)d_in[15];
    const float* box_b   = (const float*)d_in[16];
    const float* ln2_g   = (const float*)d_in[17];
    const float* ln2_b   = (const float*)d_in[18];
    const float* g1_w    = (const float*)d_in[19];
    const float* g1_b    = (const float*)d_in[20];
    const float* g2_w    = (const float*)d_in[21];
    const float* g2_b    = (const float*)d_in[22];
    const float* g3_w    = (const float*)d_in[23];
    const float* g3_b    = (const float*)d_in[24];
    float* out = (float*)d_out;
    (void)in_sizes; (void)n_in; (void)out_size; (void)ws_size;

    // -------- workspace carve (bytes, 16B aligned); total ~171 MB --------
    char* base = (char*)d_ws;
    size_t o = 0;
    auto carve = [&](size_t bytes) { char* p = base + o; o += (bytes + 15) & ~(size_t)15; return p; };
    float* x_cl    = (float*)carve(8388608);      // [2048][1024] f32 (proj out, channels-last)
    u16*   imT     = (u16*)  carve(8388608);      // [8*256][2048] bf16
    u16*   convout = (u16*)  carve(12845056);     // [512][12544] bf16
    float* fc_out  = (float*)carve(2097152);      // [512][1024] f32 (atomic acc)
    u16*   feats   = (u16*)  carve(1310720);      // [512][1280] bf16
    float* UV      = (float*)carve(5242880);      // [512][2560] f32 (atomic acc)
    u16*   wpack   = (u16*)  carve(4718592);      // [256][9216] bf16
    float* scale   = (float*)carve(1024);
    float* shift   = (float*)carve(1024);
    u16*   projwb  = (u16*)  carve(4194304);      // [1024][2048] bf16
    u16*   fcwb    = (u16*)  carve(25690112);     // [1024][12544] bf16
    u16*   g1wb    = (u16*)  carve(6553600);      // [2560][1280] bf16
    u16*   g2wb    = (u16*)  carve(3276800);      // [1280][1280] bf16
    u16*   g3wb    = (u16*)  carve(3276800);      // [1280][1280] bf16
    char*  big     = carve(84934656);             // r_pad [512][81][1024] bf16; later h1+h2
    u16*   r_pad   = (u16*)big;
    u16*   h1      = (u16*)big;                   // [16384][1280] bf16 (after conv GEMM done)
    u16*   h2      = (u16*)(big + 41943040);      // [16384][1280] bf16

    // -------- zero accumulators --------
    zero_f32<<<40, 256, 0, stream>>>(out, 10240);
    zero_f32<<<2048, 256, 0, stream>>>(fc_out, 524288);
    zero_f32<<<5120, 256, 0, stream>>>(UV, 1310720);

    // -------- weight conversion / packing --------
    cvt_bf16<<<2048, 256, 0, stream>>>(proj_w, projwb, 524288);
    cvt_bf16<<<12544, 256, 0, stream>>>(fc_w, fcwb, 3211264);
    cvt_bf16<<<1600, 256, 0, stream>>>(g2_w, g2wb, 409600);
    cvt_bf16<<<1600, 256, 0, stream>>>(g3_w, g3wb, 409600);
    pack_g1<<<3200, 256, 0, stream>>>(g1_w, g1wb);
    pack_conv<<<9216, 256, 0, stream>>>(conv_w, conv_b, bn_g, bn_b, bn_m, bn_v, wpack, scale, shift);

    // -------- 1x1 projection: transpose to bf16 then MFMA GEMM --------
    transpose_proj<<<dim3(4, 32, 8), 256, 0, stream>>>(im_feat, imT);
    gemm_bf16<0, 1, 0><<<dim3(8, 16, 1), 256, 0, stream>>>(
        imT, projwb, proj_b, nullptr, x_cl, 2048, 1024, 2048, 2048, 2048, 1024);

    // -------- ROIAlign into zero-padded bf16 buffer --------
    zero_halo<<<16384, 256, 0, stream>>>(r_pad);
    roialign_kernel<<<25088, 256, 0, stream>>>(x_cl, boxes, r_pad);

    // -------- conv3x3 + BN + ReLU (im2col MFMA), scatter to [roi][oc*49+sp] bf16 --------
    gemm_bf16<2, 3, 1><<<dim3(2, 196, 1), 256, 0, stream>>>(
        r_pad, wpack, scale, shift, convout, 25088, 256, 9216, 0, 9216, 0);

    // -------- FC (split-K 4, atomic f32): raw sum; bias+relu fused into LN1 --------
    gemm_bf16<0, 0, 3><<<dim3(8, 4, 4), 256, 0, stream>>>(
        convout, fcwb, nullptr, nullptr, fc_out, 512, 1024, 3136, 12544, 12544, 1024);

    ln1_kernel<<<512, 256, 0, stream>>>(fc_out, fc_b, ln1_g, ln1_b, feats);
    box_kernel<<<512, 256, 0, stream>>>(nboxes, box_w, box_b, ln2_g, ln2_b, feats);

    // -------- U/V GEMM (split-K 2, atomic f32): UV[m][n<1280]=U, UV[m][1280+n]=V --------
    gemm_bf16<0, 0, 3><<<dim3(20, 4, 2), 256, 0, stream>>>(
        feats, g1wb, nullptr, nullptr, UV, 512, 2560, 640, 1280, 1280, 2560);

    // -------- relation: 2 chunks of 4 images --------
    for (int h = 0; h < 2; ++h) {
        pair_kernel<<<dim3(5, 16384), 256, 0, stream>>>(UV, g1_b, h1, h * 4);
        gemm_bf16<0, 2, 4><<<dim3(10, 128, 1), 256, 0, stream>>>(
            h1, g2wb, g2_b, nullptr, h2, 16384, 1280, 1280, 1280, 1280, 1280);
        gemm_bf16<0, 2, 2><<<dim3(10, 128, 1), 256, 0, stream>>>(
            h2, g3wb, g3_b, nullptr, out + h * 4 * 1280, 16384, 1280, 1280, 1280, 1280, 1280);
    }
}

// Round 5
// 939.777 us; speedup vs baseline: 6.3084x; 1.0854x over previous
//
#include <hip/hip_runtime.h>
#include <hip/hip_bf16.h>

typedef __attribute__((ext_vector_type(8))) short short8;
typedef __attribute__((ext_vector_type(4))) float floatx4;
typedef unsigned short u16;

#define GLDS16(gp, lp) __builtin_amdgcn_global_load_lds(                        \
    (const __attribute__((address_space(1))) void*)(gp),                        \
    (__attribute__((address_space(3))) void*)(lp), 16, 0, 0)

__device__ inline u16 f2bf(float f) {
    unsigned u = __float_as_uint(f);
    unsigned r = (u + 0x7fffu + ((u >> 16) & 1u)) >> 16;
    return (u16)r;
}

// ---------------- block reduce (sum, sumsq) over 256 threads ----------------
__device__ inline void block_reduce2(float& s, float& ss) {
    #pragma unroll
    for (int o = 32; o > 0; o >>= 1) {
        s  += __shfl_down(s, o);
        ss += __shfl_down(ss, o);
    }
    __shared__ float red[8];
    const int t = threadIdx.x;
    if ((t & 63) == 0) { red[t >> 6] = s; red[4 + (t >> 6)] = ss; }
    __syncthreads();
    s  = red[0] + red[1] + red[2] + red[3];
    ss = red[4] + red[5] + red[6] + red[7];
}

// =============== bf16 MFMA GEMM, 128x128 tile, 4 waves, BK=32 ===============
// T3-minimum 2-phase: double-buffered LDS; next tile's global_load_lds issued
// BEFORE current tile's ds_read+MFMA; counted wait (vmcnt(0) for the 4 loads
// issued this iter) + raw s_barrier AFTER compute -> load latency hides under MFMA.
// C[M][N] = A(MxK) * B^T,  B stored [N][K] row-major bf16.
// T1: XCD-aware bijective block swizzle (requires gridDim.x*gridDim.y % 8 == 0).
// AMODE: 0 = A row-major bf16 [M][K] (lda)
//        2 = im2col over zero-padded r_pad bf16 [512][81][1024]; k = tap*1024+ic, m = roi*49+sp
// EPI:   0 none, 1 +P1[n], 2 relu(x+P1[n]), 3 relu(x*P1[n]+P2[n])
// CMODE: 0 C f32 row-major(ldc), 1 conv-scatter bf16 C[roi][n*49+sp], 2 colsum atomic f32 (per 4096-row img),
//        3 atomicAdd f32 row-major(ldc) [split-K], 4 C bf16 row-major(ldc)
// Split-K: kbase = blockIdx.z * Kc; loop K range = [kbase, kbase+Kc)
template<int AMODE, int EPI, int CMODE>
__global__ __launch_bounds__(256)
void gemm_bf16(const u16* __restrict__ A, const u16* __restrict__ B,
               const float* __restrict__ P1, const float* __restrict__ P2,
               void* __restrict__ Cv,
               int M, int N, int Kc, int lda, int ldb, int ldc)
{
    __shared__ short As[2][4096];   // 2 x (128 rows x 32 k) bf16 = 2 x 8 KiB
    __shared__ short Bs[2][4096];

    const int t  = threadIdx.x;
    const int w  = t >> 6, l = t & 63;
    const int wr = w >> 1, wc = w & 1;
    const int l16 = l & 15, lr = l >> 4;

    // ---- T1 XCD swizzle: bid -> (xcd = bid%8) gets contiguous chunk of tile space ----
    const int nwg = gridDim.x * gridDim.y;
    const int bid = blockIdx.y * gridDim.x + blockIdx.x;
    const int cpx = nwg >> 3;                       // nwg % 8 == 0 for all call sites
    const int sw  = (bid & 7) * cpx + (bid >> 3);
    const int n0 = (sw % gridDim.x) * 128;          // n fastest within an XCD chunk
    const int m0 = (sw / gridDim.x) * 128;
    const int kbase = blockIdx.z * Kc;

    // staging: issue it covers LDS bytes it*4096 + w*1024 + l*16
    // -> tile row = it*64 + w*16 + l/4, k-halfword offset = (l&3)*8
    const int srow  = w * 16 + (l >> 2);
    const int skoff = (l & 3) * 8;

    const u16* aRow0 = nullptr; const u16* aRow1 = nullptr;
    size_t aSp0 = 0, aSp1 = 0;
    if (AMODE == 0) {
        aRow0 = A + (size_t)(m0 + srow) * lda + kbase + skoff;
        aRow1 = A + (size_t)(m0 + 64 + srow) * lda + kbase + skoff;
    } else { // im2col: precompute spatial base (k-independent)
        const int r0 = m0 + srow, r1 = r0 + 64;
        const int roi0 = r0 / 49, sp0 = r0 - roi0 * 49;
        const int roi1 = r1 / 49, sp1 = r1 - roi1 * 49;
        aSp0 = ((size_t)roi0 * 81 + (sp0 / 7) * 9 + (sp0 % 7)) * 1024 + skoff;
        aSp1 = ((size_t)roi1 * 81 + (sp1 / 7) * 9 + (sp1 % 7)) * 1024 + skoff;
    }
    const u16* bRow0 = B + (size_t)(n0 + srow) * ldb + kbase + skoff;
    const u16* bRow1 = B + (size_t)(n0 + 64 + srow) * ldb + kbase + skoff;

    auto stage = [&](int buf, int k0) {
        if (AMODE == 0) {
            GLDS16(aRow0 + k0, As[buf] + w * 512);
            GLDS16(aRow1 + k0, As[buf] + 2048 + w * 512);
        } else {
            const int kk  = kbase + k0;
            const int tap = kk >> 10;                       // uniform per k-step (32 | 1024)
            const size_t off = (size_t)((tap / 3) * 9 + (tap % 3)) * 1024 + (kk & 1023);
            GLDS16(A + aSp0 + off, As[buf] + w * 512);
            GLDS16(A + aSp1 + off, As[buf] + 2048 + w * 512);
        }
        GLDS16(bRow0 + k0, Bs[buf] + w * 512);
        GLDS16(bRow1 + k0, Bs[buf] + 2048 + w * 512);
    };

    floatx4 acc[4][4] = {};

    // prologue: stage tile 0, wait, barrier
    stage(0, 0);
    asm volatile("s_waitcnt vmcnt(0)" ::: "memory");
    __builtin_amdgcn_s_barrier();
    __builtin_amdgcn_sched_barrier(0);

    int cur = 0;
    for (int k0 = 0; k0 < Kc; k0 += 32) {
        const int nxt = k0 + 32;
        if (nxt < Kc) stage(cur ^ 1, nxt);      // loads fly during this tile's compute

        const short* as = As[cur];
        const short* bs = Bs[cur];
        short8 af[4], bfr[4];
        #pragma unroll
        for (int i = 0; i < 4; ++i)
            af[i] = *reinterpret_cast<const short8*>(&as[(wr * 64 + i * 16 + l16) * 32 + lr * 8]);
        #pragma unroll
        for (int j = 0; j < 4; ++j)
            bfr[j] = *reinterpret_cast<const short8*>(&bs[(wc * 64 + j * 16 + l16) * 32 + lr * 8]);
        #pragma unroll
        for (int i = 0; i < 4; ++i)
            #pragma unroll
            for (int j = 0; j < 4; ++j)
                acc[i][j] = __builtin_amdgcn_mfma_f32_16x16x32_bf16(af[i], bfr[j], acc[i][j], 0, 0, 0);

        asm volatile("s_waitcnt vmcnt(0)" ::: "memory");   // next tile landed (mine)
        __builtin_amdgcn_s_barrier();                       // everyone's landed; cur consumed
        __builtin_amdgcn_sched_barrier(0);
        cur ^= 1;
    }

    const int mBase = m0 + wr * 64;
    const int nBase = n0 + wc * 64;

    if (CMODE == 2) {   // fused column-sum (EPI==2 semantics), atomic into per-image out row
        __shared__ float red2[2][128];
        float csum[4];
        #pragma unroll
        for (int j = 0; j < 4; ++j) {
            const int n = nBase + j * 16 + l16;
            const float b1 = P1[n];
            float s = 0.f;
            #pragma unroll
            for (int i = 0; i < 4; ++i)
                #pragma unroll
                for (int r = 0; r < 4; ++r)
                    s += fmaxf(acc[i][j][r] + b1, 0.f);
            s += __shfl_xor(s, 16);
            s += __shfl_xor(s, 32);
            csum[j] = s;
        }
        __syncthreads();
        if (l < 16) {
            #pragma unroll
            for (int j = 0; j < 4; ++j)
                red2[wr][wc * 64 + j * 16 + l16] = csum[j];
        }
        __syncthreads();
        float* C = (float*)Cv + (size_t)(m0 >> 12) * ldc;
        if (t < 128) atomicAdd(&C[n0 + t], red2[0][t] + red2[1][t]);
        return;
    }

    #pragma unroll
    for (int i = 0; i < 4; ++i) {
        #pragma unroll
        for (int j = 0; j < 4; ++j) {
            const int n = nBase + j * 16 + l16;
            const float b1 = (EPI >= 1) ? P1[n] : 0.f;
            const float b2 = (EPI == 3) ? P2[n] : 0.f;
            #pragma unroll
            for (int r = 0; r < 4; ++r) {
                float v = acc[i][j][r];
                if (EPI == 1)      v += b1;
                else if (EPI == 2) v = fmaxf(v + b1, 0.f);
                else if (EPI == 3) v = fmaxf(v * b1 + b2, 0.f);
                const int m = mBase + i * 16 + lr * 4 + r;
                if (CMODE == 0)      ((float*)Cv)[(size_t)m * ldc + n] = v;
                else if (CMODE == 4) ((u16*)Cv)[(size_t)m * ldc + n] = f2bf(v);
                else if (CMODE == 3) atomicAdd(&((float*)Cv)[(size_t)m * ldc + n], v);
                else if (CMODE == 1) {
                    const int roi = m / 49, sp = m - roi * 49;
                    ((u16*)Cv)[(size_t)roi * 12544 + n * 49 + sp] = f2bf(v);
                }
            }
        }
    }
}

// ---------------- im_feat [8][2048][256] f32 -> [8][256][2048] bf16 (LDS transpose) -------
__global__ __launch_bounds__(256)
void transpose_proj(const float* __restrict__ in, u16* __restrict__ out)
{
    __shared__ float tile[64][65];
    const int b = blockIdx.z;
    const int c0 = blockIdx.y * 64;    // channel tile
    const int h0 = blockIdx.x * 64;    // hw tile
    const int t = threadIdx.x;
    const float* src = in + ((size_t)b * 2048 + c0) * 256 + h0;
    #pragma unroll
    for (int p = 0; p < 16; ++p) {
        const int idx = p * 256 + t;
        const int r = idx >> 6, c = idx & 63;
        tile[r][c] = src[(size_t)r * 256 + c];
    }
    __syncthreads();
    u16* dst = out + ((size_t)b * 256 + h0) * 2048 + c0;
    #pragma unroll
    for (int p = 0; p < 16; ++p) {
        const int idx = p * 256 + t;
        const int r = idx >> 6, c = idx & 63;
        dst[(size_t)r * 2048 + c] = f2bf(tile[c][r]);
    }
}

// ---------------- zero the 1-pixel halo of r_pad [512][81][1024] bf16 ----------------
__global__ __launch_bounds__(256)
void zero_halo(u16* __restrict__ r_pad)
{
    const int blk = blockIdx.x;          // 512*32
    const int roi = blk >> 5, h = blk & 31;
    int p;
    if (h < 9)       p = h;                       // top row
    else if (h < 18) p = 72 + (h - 9);            // bottom row
    else { const int r = (h - 18) >> 1, s = (h - 18) & 1; p = (r + 1) * 9 + s * 8; }
    uint2* o = reinterpret_cast<uint2*>(r_pad + ((size_t)roi * 81 + p) * 1024);
    o[threadIdx.x] = make_uint2(0u, 0u);          // 256 * 8B = 1024 halfs
}

// ---------------- ROIAlignV2 (aligned=true), 2x2 samples/bin -> r_pad interior bf16 -------
__global__ __launch_bounds__(256)
void roialign_kernel(const float* __restrict__ x_cl, const float* __restrict__ boxes,
                     u16* __restrict__ r_pad)
{
    const int blk = blockIdx.x;          // n*49 + bin
    const int n = blk / 49, bin = blk % 49;
    const int py = bin / 7, px = bin % 7;
    const int b = n >> 6;
    const float* roi = boxes + n * 4;
    const float x1 = roi[0] * (1.f/32.f) - 0.5f;
    const float y1 = roi[1] * (1.f/32.f) - 0.5f;
    const float bw = (roi[2] - roi[0]) * (1.f/32.f) * (1.0f / 7.0f);
    const float bh = (roi[3] - roi[1]) * (1.f/32.f) * (1.0f / 7.0f);
    const int t = threadIdx.x;

    float acc[4] = {0.f, 0.f, 0.f, 0.f};
    #pragma unroll
    for (int sy = 0; sy < 2; ++sy) {
        #pragma unroll
        for (int sx = 0; sx < 2; ++sx) {
            const float yv = y1 + bh * ((float)(py * 2 + sy) + 0.5f) * 0.5f;
            const float xv = x1 + bw * ((float)(px * 2 + sx) + 0.5f) * 0.5f;
            const bool vy = (yv >= -1.0f) && (yv <= 16.0f);
            const bool vx = (xv >= -1.0f) && (xv <= 16.0f);
            if (!(vy && vx)) continue;
            float yc = fmaxf(yv, 0.f);
            int yl = (int)floorf(yc);
            int yh; if (yl >= 15) { yl = 15; yc = 15.f; yh = 15; } else yh = yl + 1;
            const float wy = yc - (float)yl;
            float xc = fmaxf(xv, 0.f);
            int xl = (int)floorf(xc);
            int xh; if (xl >= 15) { xl = 15; xc = 15.f; xh = 15; } else xh = xl + 1;
            const float wx = xc - (float)xl;

            const float w00 = (1.f - wy) * (1.f - wx), w01 = (1.f - wy) * wx;
            const float w10 = wy * (1.f - wx),         w11 = wy * wx;
            const float* p00 = x_cl + ((size_t)b * 256 + yl * 16 + xl) * 1024;
            const float* p01 = x_cl + ((size_t)b * 256 + yl * 16 + xh) * 1024;
            const float* p10 = x_cl + ((size_t)b * 256 + yh * 16 + xl) * 1024;
            const float* p11 = x_cl + ((size_t)b * 256 + yh * 16 + xh) * 1024;
            #pragma unroll
            for (int cc = 0; cc < 4; ++cc) {
                const int c = t + cc * 256;
                acc[cc] += w00 * p00[c] + w01 * p01[c] + w10 * p10[c] + w11 * p11[c];
            }
        }
    }
    u16* o = r_pad + ((size_t)n * 81 + (py + 1) * 9 + (px + 1)) * 1024;
    #pragma unroll
    for (int cc = 0; cc < 4; ++cc) o[t + cc * 256] = f2bf(acc[cc] * 0.25f);
}

// ---------------- conv weight pack (tap-major K) bf16 + BN fold ----------------
__global__ __launch_bounds__(256)
void pack_conv(const float* __restrict__ conv_w, const float* __restrict__ conv_b,
               const float* __restrict__ bn_g, const float* __restrict__ bn_b,
               const float* __restrict__ bn_m, const float* __restrict__ bn_v,
               u16* __restrict__ wpack, float* __restrict__ scale, float* __restrict__ shift)
{
    const long idx = (long)blockIdx.x * 256 + threadIdx.x;
    if (idx < 2359296L) {
        const int oc = (int)(idx / 9216), k = (int)(idx % 9216);
        const int tap = k >> 10, ic = k & 1023;
        wpack[idx] = f2bf(conv_w[(long)oc * 9216 + ic * 9 + tap]);
    }
    if (idx < 256) {
        const float s = bn_g[idx] * rsqrtf(bn_v[idx] + 1e-5f);
        scale[idx] = s;
        shift[idx] = (conv_b[idx] - bn_m[idx]) * s + bn_b[idx];
    }
}

// ---------------- straight f32 -> bf16 convert (xN/4) ----------------
__global__ __launch_bounds__(256)
void cvt_bf16(const float* __restrict__ in, u16* __restrict__ out, int n4)
{
    const int i = blockIdx.x * 256 + threadIdx.x;
    if (i < n4) {
        const float4 v = reinterpret_cast<const float4*>(in)[i];
        ushort4 o; o.x = f2bf(v.x); o.y = f2bf(v.y); o.z = f2bf(v.z); o.w = f2bf(v.w);
        reinterpret_cast<ushort4*>(out)[i] = o;
    }
}

// ---------------- g1_w [1280][2560] f32 -> [2560][1280] bf16 (U rows then V rows) ----------
__global__ __launch_bounds__(256)
void pack_g1(const float* __restrict__ g1w, u16* __restrict__ out)
{
    const int j = blockIdx.x * 256 + threadIdx.x;   // 2560 * 320
    if (j >= 2560 * 320) return;
    const int np = j / 320, k4 = (j - np * 320) * 4;
    const int srow = (np < 1280) ? np : np - 1280;
    const int soff = (np < 1280) ? 0 : 1280;
    const float4 v = *reinterpret_cast<const float4*>(&g1w[(size_t)srow * 2560 + soff + k4]);
    ushort4 o; o.x = f2bf(v.x); o.y = f2bf(v.y); o.z = f2bf(v.z); o.w = f2bf(v.w);
    *reinterpret_cast<ushort4*>(&out[(size_t)np * 1280 + k4]) = o;
}

// ---------------- fc bias + relu + LayerNorm(1024) -> feats[:, :1024] bf16 ----------------
__global__ __launch_bounds__(256)
void ln1_kernel(const float* __restrict__ in, const float* __restrict__ fb,
                const float* __restrict__ g, const float* __restrict__ b,
                u16* __restrict__ feats)
{
    const int n = blockIdx.x, t = threadIdx.x;
    float4 v = *reinterpret_cast<const float4*>(in + (size_t)n * 1024 + t * 4);
    const float4 bb = *reinterpret_cast<const float4*>(fb + t * 4);
    v.x = fmaxf(v.x + bb.x, 0.f); v.y = fmaxf(v.y + bb.y, 0.f);
    v.z = fmaxf(v.z + bb.z, 0.f); v.w = fmaxf(v.w + bb.w, 0.f);
    float s  = v.x + v.y + v.z + v.w;
    float ss = v.x*v.x + v.y*v.y + v.z*v.z + v.w*v.w;
    block_reduce2(s, ss);
    const float mu  = s * (1.f / 1024.f);
    const float var = ss * (1.f / 1024.f) - mu * mu;
    const float r   = rsqrtf(var + 1e-5f);
    const float4 gp = *reinterpret_cast<const float4*>(g + t * 4);
    const float4 bp = *reinterpret_cast<const float4*>(b + t * 4);
    ushort4 o;
    o.x = f2bf((v.x - mu) * r * gp.x + bp.x);
    o.y = f2bf((v.y - mu) * r * gp.y + bp.y);
    o.z = f2bf((v.z - mu) * r * gp.z + bp.z);
    o.w = f2bf((v.w - mu) * r * gp.w + bp.w);
    *reinterpret_cast<ushort4*>(feats + (size_t)n * 1280 + t * 4) = o;
}

// ---------------- box branch -> feats[:, 1024:1280] bf16 ----------------
__global__ __launch_bounds__(256)
void box_kernel(const float* __restrict__ nb, const float* __restrict__ bw,
                const float* __restrict__ bb, const float* __restrict__ g,
                const float* __restrict__ be, u16* __restrict__ feats)
{
    const int n = blockIdx.x, j = threadIdx.x;
    const float4 q = *reinterpret_cast<const float4*>(nb + n * 4);
    const float4 w = *reinterpret_cast<const float4*>(bw + j * 4);
    const float v = (q.x * 2.f - 1.f) * w.x + (q.y * 2.f - 1.f) * w.y
                  + (q.z * 2.f - 1.f) * w.z + (q.w * 2.f - 1.f) * w.w + bb[j];
    float s = v, ss = v * v;
    block_reduce2(s, ss);
    const float mu  = s * (1.f / 256.f);
    const float var = ss * (1.f / 256.f) - mu * mu;
    feats[(size_t)n * 1280 + 1024 + j] = f2bf((v - mu) * rsqrtf(var + 1e-5f) * g[j] + be[j]);
}

// ---------------- pair expansion (4-image chunk): h1 = relu(U[b]+V[a]+g1_b) bf16 ----------
__global__ __launch_bounds__(256)
void pair_kernel(const float* __restrict__ UV, const float* __restrict__ g1b,
                 u16* __restrict__ h1, int imgbase)
{
    const int pidx = blockIdx.y;                       // 0..16383
    const int img = imgbase + (pidx >> 12);
    const int a = (pidx >> 6) & 63, b = pidx & 63;
    const int col = blockIdx.x * 256 + threadIdx.x;    // grid.x = 5
    const float v = UV[(size_t)(img * 64 + b) * 2560 + col]
                  + UV[(size_t)(img * 64 + a) * 2560 + 1280 + col] + g1b[col];
    h1[(size_t)pidx * 1280 + col] = f2bf(fmaxf(v, 0.f));
}

__global__ void zero_f32(float* __restrict__ p, int n) {
    const int i = blockIdx.x * 256 + threadIdx.x;
    if (i < n) p[i] = 0.f;
}

// =======================================================================================
extern "C" void kernel_launch(void* const* d_in, const int* in_sizes, int n_in,
                              void* d_out, int out_size, void* d_ws, size_t ws_size,
                              hipStream_t stream)
{
    const float* im_feat = (const float*)d_in[0];
    const float* boxes   = (const float*)d_in[1];
    const float* nboxes  = (const float*)d_in[2];
    const float* proj_w  = (const float*)d_in[3];
    const float* proj_b  = (const float*)d_in[4];
    const float* conv_w  = (const float*)d_in[5];
    const float* conv_b  = (const float*)d_in[6];
    const float* bn_g    = (const float*)d_in[7];
    const float* bn_b    = (const float*)d_in[8];
    const float* bn_m    = (const float*)d_in[9];
    const float* bn_v    = (const float*)d_in[10];
    const float* fc_w    = (const float*)d_in[11];
    const float* fc_b    = (const float*)d_in[12];
    const float* ln1_g   = (const float*)d_in[13];
    const float* ln1_b   = (const float*)d_in[14];
    const float* box_w   = (const float*)d_in[15];
    const float* box_b   = (const float*)d_in[16];
    const float* ln2_g   = (const float*)d_in[17];
    const float* ln2_b   = (const float*)d_in[18];
    const float* g1_w    = (const float*)d_in[19];
    const float* g1_b    = (const float*)d_in[20];
    const float* g2_w    = (const float*)d_in[21];
    const float* g2_b    = (const float*)d_in[22];
    const float* g3_w    = (const float*)d_in[23];
    const float* g3_b    = (const float*)d_in[24];
    float* out = (float*)d_out;
    (void)in_sizes; (void)n_in; (void)out_size; (void)ws_size;

    // -------- workspace carve (bytes, 16B aligned); total ~171 MB --------
    char* base = (char*)d_ws;
    size_t o = 0;
    auto carve = [&](size_t bytes) { char* p = base + o; o += (bytes + 15) & ~(size_t)15; return p; };
    float* x_cl    = (float*)carve(8388608);      // [2048][1024] f32 (proj out, channels-last)
    u16*   imT     = (u16*)  carve(8388608);      // [8*256][2048] bf16
    u16*   convout = (u16*)  carve(12845056);     // [512][12544] bf16
    float* fc_out  = (float*)carve(2097152);      // [512][1024] f32 (atomic acc)
    u16*   feats   = (u16*)  carve(1310720);      // [512][1280] bf16
    float* UV      = (float*)carve(5242880);      // [512][2560] f32 (atomic acc)
    u16*   wpack   = (u16*)  carve(4718592);      // [256][9216] bf16
    float* scale   = (float*)carve(1024);
    float* shift   = (float*)carve(1024);
    u16*   projwb  = (u16*)  carve(4194304);      // [1024][2048] bf16
    u16*   fcwb    = (u16*)  carve(25690112);     // [1024][12544] bf16
    u16*   g1wb    = (u16*)  carve(6553600);      // [2560][1280] bf16
    u16*   g2wb    = (u16*)  carve(3276800);      // [1280][1280] bf16
    u16*   g3wb    = (u16*)  carve(3276800);      // [1280][1280] bf16
    char*  big     = carve(84934656);             // r_pad [512][81][1024] bf16; later h1+h2
    u16*   r_pad   = (u16*)big;
    u16*   h1      = (u16*)big;                   // [16384][1280] bf16 (after conv GEMM done)
    u16*   h2      = (u16*)(big + 41943040);      // [16384][1280] bf16

    // -------- zero accumulators --------
    zero_f32<<<40, 256, 0, stream>>>(out, 10240);
    zero_f32<<<2048, 256, 0, stream>>>(fc_out, 524288);
    zero_f32<<<5120, 256, 0, stream>>>(UV, 1310720);

    // -------- weight conversion / packing --------
    cvt_bf16<<<2048, 256, 0, stream>>>(proj_w, projwb, 524288);
    cvt_bf16<<<12544, 256, 0, stream>>>(fc_w, fcwb, 3211264);
    cvt_bf16<<<1600, 256, 0, stream>>>(g2_w, g2wb, 409600);
    cvt_bf16<<<1600, 256, 0, stream>>>(g3_w, g3wb, 409600);
    pack_g1<<<3200, 256, 0, stream>>>(g1_w, g1wb);
    pack_conv<<<9216, 256, 0, stream>>>(conv_w, conv_b, bn_g, bn_b, bn_m, bn_v, wpack, scale, shift);

    // -------- 1x1 projection: transpose to bf16 then MFMA GEMM --------
    transpose_proj<<<dim3(4, 32, 8), 256, 0, stream>>>(im_feat, imT);
    gemm_bf16<0, 1, 0><<<dim3(8, 16, 1), 256, 0, stream>>>(
        imT, projwb, proj_b, nullptr, x_cl, 2048, 1024, 2048, 2048, 2048, 1024);

    // -------- ROIAlign into zero-padded bf16 buffer --------
    zero_halo<<<16384, 256, 0, stream>>>(r_pad);
    roialign_kernel<<<25088, 256, 0, stream>>>(x_cl, boxes, r_pad);

    // -------- conv3x3 + BN + ReLU (im2col MFMA), scatter to [roi][oc*49+sp] bf16 --------
    gemm_bf16<2, 3, 1><<<dim3(2, 196, 1), 256, 0, stream>>>(
        r_pad, wpack, scale, shift, convout, 25088, 256, 9216, 0, 9216, 0);

    // -------- FC (split-K 4, atomic f32): raw sum; bias+relu fused into LN1 --------
    gemm_bf16<0, 0, 3><<<dim3(8, 4, 4), 256, 0, stream>>>(
        convout, fcwb, nullptr, nullptr, fc_out, 512, 1024, 3136, 12544, 12544, 1024);

    ln1_kernel<<<512, 256, 0, stream>>>(fc_out, fc_b, ln1_g, ln1_b, feats);
    box_kernel<<<512, 256, 0, stream>>>(nboxes, box_w, box_b, ln2_g, ln2_b, feats);

    // -------- U/V GEMM (split-K 2, atomic f32): UV[m][n<1280]=U, UV[m][1280+n]=V --------
    gemm_bf16<0, 0, 3><<<dim3(20, 4, 2), 256, 0, stream>>>(
        feats, g1wb, nullptr, nullptr, UV, 512, 2560, 640, 1280, 1280, 2560);

    // -------- relation: 2 chunks of 4 images --------
    for (int h = 0; h < 2; ++h) {
        pair_kernel<<<dim3(5, 16384), 256, 0, stream>>>(UV, g1_b, h1, h * 4);
        gemm_bf16<0, 2, 4><<<dim3(10, 128, 1), 256, 0, stream>>>(
            h1, g2wb, g2_b, nullptr, h2, 16384, 1280, 1280, 1280, 1280, 1280);
        gemm_bf16<0, 2, 2><<<dim3(10, 128, 1), 256, 0, stream>>>(
            h2, g3wb, g3_b, nullptr, out + h * 4 * 1280, 16384, 1280, 1280, 1280, 1280, 1280);
    }
}

// Round 6
// 937.202 us; speedup vs baseline: 6.3258x; 1.0027x over previous
//
#include <hip/hip_runtime.h>
#include <hip/hip_bf16.h>

typedef __attribute__((ext_vector_type(8))) short short8;
typedef __attribute__((ext_vector_type(4))) float floatx4;
typedef unsigned short u16;

#define GLDS16(gp, lp) __builtin_amdgcn_global_load_lds(                        \
    (const __attribute__((address_space(1))) void*)(gp),                        \
    (__attribute__((address_space(3))) void*)(lp), 16, 0, 0)

__device__ inline u16 f2bf(float f) {
    unsigned u = __float_as_uint(f);
    unsigned r = (u + 0x7fffu + ((u >> 16) & 1u)) >> 16;
    return (u16)r;
}

// ---------------- block reduce (sum, sumsq) over 256 threads ----------------
__device__ inline void block_reduce2(float& s, float& ss) {
    #pragma unroll
    for (int o = 32; o > 0; o >>= 1) {
        s  += __shfl_down(s, o);
        ss += __shfl_down(ss, o);
    }
    __shared__ float red[8];
    const int t = threadIdx.x;
    if ((t & 63) == 0) { red[t >> 6] = s; red[4 + (t >> 6)] = ss; }
    __syncthreads();
    s  = red[0] + red[1] + red[2] + red[3];
    ss = red[4] + red[5] + red[6] + red[7];
}

// =============== bf16 MFMA GEMM, 128x128 tile, 4 waves, BK=32 ===============
// T4 ring-3: triple-buffered LDS, counted vmcnt(8) in steady state (never 0 in
//   main loop); 12 loads in flight -> each tile's loads get ~2 K-steps to land.
// T2 slot-swizzle: 64B LDS rows = 4 x 16B slots; data slot s of row r lives at
//   LDS slot s^(r&3). Applied via pre-swizzled GLOBAL source (GLDS dest linear,
//   rule 21) + XOR on ds_read. Read conflicts 8-way -> 2-way (free).
// T5: setprio(1) around MFMA cluster.
// T1: XCD-aware bijective block swizzle (requires gridDim.x*gridDim.y % 8 == 0).
// C[M][N] = A(MxK) * B^T,  B stored [N][K] row-major bf16.
// AMODE: 0 = A row-major bf16 [M][K] (lda)
//        2 = im2col over zero-padded r_pad bf16 [512][81][1024]; k = tap*1024+ic, m = roi*49+sp
// EPI:   0 none, 1 +P1[n], 2 relu(x+P1[n]), 3 relu(x*P1[n]+P2[n])
// CMODE: 0 C f32 row-major(ldc), 1 conv-scatter bf16 C[roi][n*49+sp], 2 colsum atomic f32 (per 4096-row img),
//        3 atomicAdd f32 row-major(ldc) [split-K], 4 C bf16 row-major(ldc)
// Split-K: kbase = blockIdx.z * Kc. Requires Kc % 32 == 0 and Kc/32 >= 3.
template<int AMODE, int EPI, int CMODE>
__global__ __launch_bounds__(256)
void gemm_bf16(const u16* __restrict__ A, const u16* __restrict__ B,
               const float* __restrict__ P1, const float* __restrict__ P2,
               void* __restrict__ Cv,
               int M, int N, int Kc, int lda, int ldb, int ldc)
{
    __shared__ short As[3][4096];   // 3 x (128 rows x 32 k) bf16 = 3 x 8 KiB
    __shared__ short Bs[3][4096];

    const int t  = threadIdx.x;
    const int w  = t >> 6, l = t & 63;
    const int wr = w >> 1, wc = w & 1;
    const int l16 = l & 15, lr = l >> 4;

    // ---- T1 XCD swizzle ----
    const int nwg = gridDim.x * gridDim.y;
    const int bid = blockIdx.y * gridDim.x + blockIdx.x;
    const int cpx = nwg >> 3;                       // nwg % 8 == 0 for all call sites
    const int sw  = (bid & 7) * cpx + (bid >> 3);
    const int n0 = (sw % gridDim.x) * 128;          // n fastest within an XCD chunk
    const int m0 = (sw / gridDim.x) * 128;
    const int kbase = blockIdx.z * Kc;

    // staging: GLDS dest is linear (w*1024 + l*16 bytes per 64-row half-tile):
    //   row = w*16 + l/4, LDS slot = l&3. Source fetches data slot (l&3)^(row&3)
    //   -> LDS[row][slot] holds data slot slot^(row&3)  (T2 involution).
    const int srow  = w * 16 + (l >> 2);
    const int skoff = (((l & 3) ^ ((l >> 2) & 3)) * 8);   // halfwords

    const u16* aRow0 = nullptr; const u16* aRow1 = nullptr;
    size_t aSp0 = 0, aSp1 = 0;
    if (AMODE == 0) {
        aRow0 = A + (size_t)(m0 + srow) * lda + kbase + skoff;
        aRow1 = A + (size_t)(m0 + 64 + srow) * lda + kbase + skoff;
    } else { // im2col: precompute spatial base (k-independent)
        const int r0 = m0 + srow, r1 = r0 + 64;
        const int roi0 = r0 / 49, sp0 = r0 - roi0 * 49;
        const int roi1 = r1 / 49, sp1 = r1 - roi1 * 49;
        aSp0 = ((size_t)roi0 * 81 + (sp0 / 7) * 9 + (sp0 % 7)) * 1024 + skoff;
        aSp1 = ((size_t)roi1 * 81 + (sp1 / 7) * 9 + (sp1 % 7)) * 1024 + skoff;
    }
    const u16* bRow0 = B + (size_t)(n0 + srow) * ldb + kbase + skoff;
    const u16* bRow1 = B + (size_t)(n0 + 64 + srow) * ldb + kbase + skoff;

    auto stage = [&](int buf, int k0) {
        if (AMODE == 0) {
            GLDS16(aRow0 + k0, As[buf] + w * 512);
            GLDS16(aRow1 + k0, As[buf] + 2048 + w * 512);
        } else {
            const int kk  = kbase + k0;
            const int tap = kk >> 10;                       // uniform per k-step (32 | 1024)
            const size_t off = (size_t)((tap / 3) * 9 + (tap % 3)) * 1024 + (kk & 1023);
            GLDS16(A + aSp0 + off, As[buf] + w * 512);
            GLDS16(A + aSp1 + off, As[buf] + 2048 + w * 512);
        }
        GLDS16(bRow0 + k0, Bs[buf] + w * 512);
        GLDS16(bRow1 + k0, Bs[buf] + 2048 + w * 512);
    };

    floatx4 acc[4][4] = {};

    // T2 swizzled read offset (halfwords): row*32 + (lr^(row&3))*8
    auto compute = [&](int buf) {
        const short* as = As[buf];
        const short* bs = Bs[buf];
        short8 af[4], bfr[4];
        #pragma unroll
        for (int i = 0; i < 4; ++i) {
            const int row = wr * 64 + i * 16 + l16;
            af[i] = *reinterpret_cast<const short8*>(&as[row * 32 + ((lr ^ (row & 3)) * 8)]);
        }
        #pragma unroll
        for (int j = 0; j < 4; ++j) {
            const int row = wc * 64 + j * 16 + l16;
            bfr[j] = *reinterpret_cast<const short8*>(&bs[row * 32 + ((lr ^ (row & 3)) * 8)]);
        }
        __builtin_amdgcn_s_setprio(1);
        #pragma unroll
        for (int i = 0; i < 4; ++i)
            #pragma unroll
            for (int j = 0; j < 4; ++j)
                acc[i][j] = __builtin_amdgcn_mfma_f32_16x16x32_bf16(af[i], bfr[j], acc[i][j], 0, 0, 0);
        __builtin_amdgcn_s_setprio(0);
    };

    const int nsteps = Kc >> 5;          // >= 3 at every call site

    // prologue: 3 tiles in flight (12 loads)
    stage(0, 0); stage(1, 32); stage(2, 64);

    // main loop: steady-state vmcnt(8) -> oldest 4 (this tile) have landed
    for (int i = 0; i < nsteps - 2; ++i) {
        asm volatile("s_waitcnt vmcnt(8)" ::: "memory");
        __builtin_amdgcn_s_barrier();
        __builtin_amdgcn_sched_barrier(0);
        compute(i % 3);
        __builtin_amdgcn_sched_barrier(0);
        __builtin_amdgcn_s_barrier();        // all waves done reading slot i%3
        __builtin_amdgcn_sched_barrier(0);
        if (i < nsteps - 3) stage(i % 3, (i + 3) * 32);
    }
    // peeled tail: no more staging; counts drop 8 -> 4 -> 0
    {
        const int i = nsteps - 2;
        asm volatile("s_waitcnt vmcnt(4)" ::: "memory");
        __builtin_amdgcn_s_barrier();
        __builtin_amdgcn_sched_barrier(0);
        compute(i % 3);
    }
    {
        const int i = nsteps - 1;
        asm volatile("s_waitcnt vmcnt(0)" ::: "memory");
        __builtin_amdgcn_s_barrier();
        __builtin_amdgcn_sched_barrier(0);
        compute(i % 3);
    }

    const int mBase = m0 + wr * 64;
    const int nBase = n0 + wc * 64;

    if (CMODE == 2) {   // fused column-sum (EPI==2 semantics), atomic into per-image out row
        __shared__ float red2[2][128];
        float csum[4];
        #pragma unroll
        for (int j = 0; j < 4; ++j) {
            const int n = nBase + j * 16 + l16;
            const float b1 = P1[n];
            float s = 0.f;
            #pragma unroll
            for (int i = 0; i < 4; ++i)
                #pragma unroll
                for (int r = 0; r < 4; ++r)
                    s += fmaxf(acc[i][j][r] + b1, 0.f);
            s += __shfl_xor(s, 16);
            s += __shfl_xor(s, 32);
            csum[j] = s;
        }
        __syncthreads();
        if (l < 16) {
            #pragma unroll
            for (int j = 0; j < 4; ++j)
                red2[wr][wc * 64 + j * 16 + l16] = csum[j];
        }
        __syncthreads();
        float* C = (float*)Cv + (size_t)(m0 >> 12) * ldc;
        if (t < 128) atomicAdd(&C[n0 + t], red2[0][t] + red2[1][t]);
        return;
    }

    #pragma unroll
    for (int i = 0; i < 4; ++i) {
        #pragma unroll
        for (int j = 0; j < 4; ++j) {
            const int n = nBase + j * 16 + l16;
            const float b1 = (EPI >= 1) ? P1[n] : 0.f;
            const float b2 = (EPI == 3) ? P2[n] : 0.f;
            #pragma unroll
            for (int r = 0; r < 4; ++r) {
                float v = acc[i][j][r];
                if (EPI == 1)      v += b1;
                else if (EPI == 2) v = fmaxf(v + b1, 0.f);
                else if (EPI == 3) v = fmaxf(v * b1 + b2, 0.f);
                const int m = mBase + i * 16 + lr * 4 + r;
                if (CMODE == 0)      ((float*)Cv)[(size_t)m * ldc + n] = v;
                else if (CMODE == 4) ((u16*)Cv)[(size_t)m * ldc + n] = f2bf(v);
                else if (CMODE == 3) atomicAdd(&((float*)Cv)[(size_t)m * ldc + n], v);
                else if (CMODE == 1) {
                    const int roi = m / 49, sp = m - roi * 49;
                    ((u16*)Cv)[(size_t)roi * 12544 + n * 49 + sp] = f2bf(v);
                }
            }
        }
    }
}

// ---------------- im_feat [8][2048][256] f32 -> [8][256][2048] bf16 (LDS transpose) -------
__global__ __launch_bounds__(256)
void transpose_proj(const float* __restrict__ in, u16* __restrict__ out)
{
    __shared__ float tile[64][65];
    const int b = blockIdx.z;
    const int c0 = blockIdx.y * 64;    // channel tile
    const int h0 = blockIdx.x * 64;    // hw tile
    const int t = threadIdx.x;
    const float* src = in + ((size_t)b * 2048 + c0) * 256 + h0;
    #pragma unroll
    for (int p = 0; p < 16; ++p) {
        const int idx = p * 256 + t;
        const int r = idx >> 6, c = idx & 63;
        tile[r][c] = src[(size_t)r * 256 + c];
    }
    __syncthreads();
    u16* dst = out + ((size_t)b * 256 + h0) * 2048 + c0;
    #pragma unroll
    for (int p = 0; p < 16; ++p) {
        const int idx = p * 256 + t;
        const int r = idx >> 6, c = idx & 63;
        dst[(size_t)r * 2048 + c] = f2bf(tile[c][r]);
    }
}

// ---------------- zero the 1-pixel halo of r_pad [512][81][1024] bf16 ----------------
__global__ __launch_bounds__(256)
void zero_halo(u16* __restrict__ r_pad)
{
    const int blk = blockIdx.x;          // 512*32
    const int roi = blk >> 5, h = blk & 31;
    int p;
    if (h < 9)       p = h;                       // top row
    else if (h < 18) p = 72 + (h - 9);            // bottom row
    else { const int r = (h - 18) >> 1, s = (h - 18) & 1; p = (r + 1) * 9 + s * 8; }
    uint2* o = reinterpret_cast<uint2*>(r_pad + ((size_t)roi * 81 + p) * 1024);
    o[threadIdx.x] = make_uint2(0u, 0u);          // 256 * 8B = 1024 halfs
}

// ---------------- ROIAlignV2 (aligned=true), 2x2 samples/bin -> r_pad interior bf16 -------
__global__ __launch_bounds__(256)
void roialign_kernel(const float* __restrict__ x_cl, const float* __restrict__ boxes,
                     u16* __restrict__ r_pad)
{
    const int blk = blockIdx.x;          // n*49 + bin
    const int n = blk / 49, bin = blk % 49;
    const int py = bin / 7, px = bin % 7;
    const int b = n >> 6;
    const float* roi = boxes + n * 4;
    const float x1 = roi[0] * (1.f/32.f) - 0.5f;
    const float y1 = roi[1] * (1.f/32.f) - 0.5f;
    const float bw = (roi[2] - roi[0]) * (1.f/32.f) * (1.0f / 7.0f);
    const float bh = (roi[3] - roi[1]) * (1.f/32.f) * (1.0f / 7.0f);
    const int t = threadIdx.x;

    float acc[4] = {0.f, 0.f, 0.f, 0.f};
    #pragma unroll
    for (int sy = 0; sy < 2; ++sy) {
        #pragma unroll
        for (int sx = 0; sx < 2; ++sx) {
            const float yv = y1 + bh * ((float)(py * 2 + sy) + 0.5f) * 0.5f;
            const float xv = x1 + bw * ((float)(px * 2 + sx) + 0.5f) * 0.5f;
            const bool vy = (yv >= -1.0f) && (yv <= 16.0f);
            const bool vx = (xv >= -1.0f) && (xv <= 16.0f);
            if (!(vy && vx)) continue;
            float yc = fmaxf(yv, 0.f);
            int yl = (int)floorf(yc);
            int yh; if (yl >= 15) { yl = 15; yc = 15.f; yh = 15; } else yh = yl + 1;
            const float wy = yc - (float)yl;
            float xc = fmaxf(xv, 0.f);
            int xl = (int)floorf(xc);
            int xh; if (xl >= 15) { xl = 15; xc = 15.f; xh = 15; } else xh = xl + 1;
            const float wx = xc - (float)xl;

            const float w00 = (1.f - wy) * (1.f - wx), w01 = (1.f - wy) * wx;
            const float w10 = wy * (1.f - wx),         w11 = wy * wx;
            const float* p00 = x_cl + ((size_t)b * 256 + yl * 16 + xl) * 1024;
            const float* p01 = x_cl + ((size_t)b * 256 + yl * 16 + xh) * 1024;
            const float* p10 = x_cl + ((size_t)b * 256 + yh * 16 + xl) * 1024;
            const float* p11 = x_cl + ((size_t)b * 256 + yh * 16 + xh) * 1024;
            #pragma unroll
            for (int cc = 0; cc < 4; ++cc) {
                const int c = t + cc * 256;
                acc[cc] += w00 * p00[c] + w01 * p01[c] + w10 * p10[c] + w11 * p11[c];
            }
        }
    }
    u16* o = r_pad + ((size_t)n * 81 + (py + 1) * 9 + (px + 1)) * 1024;
    #pragma unroll
    for (int cc = 0; cc < 4; ++cc) o[t + cc * 256] = f2bf(acc[cc] * 0.25f);
}

// ---------------- conv weight pack (tap-major K) bf16 + BN fold ----------------
__global__ __launch_bounds__(256)
void pack_conv(const float* __restrict__ conv_w, const float* __restrict__ conv_b,
               const float* __restrict__ bn_g, const float* __restrict__ bn_b,
               const float* __restrict__ bn_m, const float* __restrict__ bn_v,
               u16* __restrict__ wpack, float* __restrict__ scale, float* __restrict__ shift)
{
    const long idx = (long)blockIdx.x * 256 + threadIdx.x;
    if (idx < 2359296L) {
        const int oc = (int)(idx / 9216), k = (int)(idx % 9216);
        const int tap = k >> 10, ic = k & 1023;
        wpack[idx] = f2bf(conv_w[(long)oc * 9216 + ic * 9 + tap]);
    }
    if (idx < 256) {
        const float s = bn_g[idx] * rsqrtf(bn_v[idx] + 1e-5f);
        scale[idx] = s;
        shift[idx] = (conv_b[idx] - bn_m[idx]) * s + bn_b[idx];
    }
}

// ---------------- straight f32 -> bf16 convert (xN/4) ----------------
__global__ __launch_bounds__(256)
void cvt_bf16(const float* __restrict__ in, u16* __restrict__ out, int n4)
{
    const int i = blockIdx.x * 256 + threadIdx.x;
    if (i < n4) {
        const float4 v = reinterpret_cast<const float4*>(in)[i];
        ushort4 o; o.x = f2bf(v.x); o.y = f2bf(v.y); o.z = f2bf(v.z); o.w = f2bf(v.w);
        reinterpret_cast<ushort4*>(out)[i] = o;
    }
}

// ---------------- g1_w [1280][2560] f32 -> [2560][1280] bf16 (U rows then V rows) ----------
__global__ __launch_bounds__(256)
void pack_g1(const float* __restrict__ g1w, u16* __restrict__ out)
{
    const int j = blockIdx.x * 256 + threadIdx.x;   // 2560 * 320
    if (j >= 2560 * 320) return;
    const int np = j / 320, k4 = (j - np * 320) * 4;
    const int srow = (np < 1280) ? np : np - 1280;
    const int soff = (np < 1280) ? 0 : 1280;
    const float4 v = *reinterpret_cast<const float4*>(&g1w[(size_t)srow * 2560 + soff + k4]);
    ushort4 o; o.x = f2bf(v.x); o.y = f2bf(v.y); o.z = f2bf(v.z); o.w = f2bf(v.w);
    *reinterpret_cast<ushort4*>(&out[(size_t)np * 1280 + k4]) = o;
}

// ---------------- fc bias + relu + LayerNorm(1024) -> feats[:, :1024] bf16 ----------------
__global__ __launch_bounds__(256)
void ln1_kernel(const float* __restrict__ in, const float* __restrict__ fb,
                const float* __restrict__ g, const float* __restrict__ b,
                u16* __restrict__ feats)
{
    const int n = blockIdx.x, t = threadIdx.x;
    float4 v = *reinterpret_cast<const float4*>(in + (size_t)n * 1024 + t * 4);
    const float4 bb = *reinterpret_cast<const float4*>(fb + t * 4);
    v.x = fmaxf(v.x + bb.x, 0.f); v.y = fmaxf(v.y + bb.y, 0.f);
    v.z = fmaxf(v.z + bb.z, 0.f); v.w = fmaxf(v.w + bb.w, 0.f);
    float s  = v.x + v.y + v.z + v.w;
    float ss = v.x*v.x + v.y*v.y + v.z*v.z + v.w*v.w;
    block_reduce2(s, ss);
    const float mu  = s * (1.f / 1024.f);
    const float var = ss * (1.f / 1024.f) - mu * mu;
    const float r   = rsqrtf(var + 1e-5f);
    const float4 gp = *reinterpret_cast<const float4*>(g + t * 4);
    const float4 bp = *reinterpret_cast<const float4*>(b + t * 4);
    ushort4 o;
    o.x = f2bf((v.x - mu) * r * gp.x + bp.x);
    o.y = f2bf((v.y - mu) * r * gp.y + bp.y);
    o.z = f2bf((v.z - mu) * r * gp.z + bp.z);
    o.w = f2bf((v.w - mu) * r * gp.w + bp.w);
    *reinterpret_cast<ushort4*>(feats + (size_t)n * 1280 + t * 4) = o;
}

// ---------------- box branch -> feats[:, 1024:1280] bf16 ----------------
__global__ __launch_bounds__(256)
void box_kernel(const float* __restrict__ nb, const float* __restrict__ bw,
                const float* __restrict__ bb, const float* __restrict__ g,
                const float* __restrict__ be, u16* __restrict__ feats)
{
    const int n = blockIdx.x, j = threadIdx.x;
    const float4 q = *reinterpret_cast<const float4*>(nb + n * 4);
    const float4 w = *reinterpret_cast<const float4*>(bw + j * 4);
    const float v = (q.x * 2.f - 1.f) * w.x + (q.y * 2.f - 1.f) * w.y
                  + (q.z * 2.f - 1.f) * w.z + (q.w * 2.f - 1.f) * w.w + bb[j];
    float s = v, ss = v * v;
    block_reduce2(s, ss);
    const float mu  = s * (1.f / 256.f);
    const float var = ss * (1.f / 256.f) - mu * mu;
    feats[(size_t)n * 1280 + 1024 + j] = f2bf((v - mu) * rsqrtf(var + 1e-5f) * g[j] + be[j]);
}

// ---------------- pair expansion (4-image chunk): h1 = relu(U[b]+V[a]+g1_b) bf16 ----------
__global__ __launch_bounds__(256)
void pair_kernel(const float* __restrict__ UV, const float* __restrict__ g1b,
                 u16* __restrict__ h1, int imgbase)
{
    const int pidx = blockIdx.y;                       // 0..16383
    const int img = imgbase + (pidx >> 12);
    const int a = (pidx >> 6) & 63, b = pidx & 63;
    const int col = blockIdx.x * 256 + threadIdx.x;    // grid.x = 5
    const float v = UV[(size_t)(img * 64 + b) * 2560 + col]
                  + UV[(size_t)(img * 64 + a) * 2560 + 1280 + col] + g1b[col];
    h1[(size_t)pidx * 1280 + col] = f2bf(fmaxf(v, 0.f));
}

__global__ void zero_f32(float* __restrict__ p, int n) {
    const int i = blockIdx.x * 256 + threadIdx.x;
    if (i < n) p[i] = 0.f;
}

// =======================================================================================
extern "C" void kernel_launch(void* const* d_in, const int* in_sizes, int n_in,
                              void* d_out, int out_size, void* d_ws, size_t ws_size,
                              hipStream_t stream)
{
    const float* im_feat = (const float*)d_in[0];
    const float* boxes   = (const float*)d_in[1];
    const float* nboxes  = (const float*)d_in[2];
    const float* proj_w  = (const float*)d_in[3];
    const float* proj_b  = (const float*)d_in[4];
    const float* conv_w  = (const float*)d_in[5];
    const float* conv_b  = (const float*)d_in[6];
    const float* bn_g    = (const float*)d_in[7];
    const float* bn_b    = (const float*)d_in[8];
    const float* bn_m    = (const float*)d_in[9];
    const float* bn_v    = (const float*)d_in[10];
    const float* fc_w    = (const float*)d_in[11];
    const float* fc_b    = (const float*)d_in[12];
    const float* ln1_g   = (const float*)d_in[13];
    const float* ln1_b   = (const float*)d_in[14];
    const float* box_w   = (const float*)d_in[15];
    const float* box_b   = (const float*)d_in[16];
    const float* ln2_g   = (const float*)d_in[17];
    const float* ln2_b   = (const float*)d_in[18];
    const float* g1_w    = (const float*)d_in[19];
    const float* g1_b    = (const float*)d_in[20];
    const float* g2_w    = (const float*)d_in[21];
    const float* g2_b    = (const float*)d_in[22];
    const float* g3_w    = (const float*)d_in[23];
    const float* g3_b    = (const float*)d_in[24];
    float* out = (float*)d_out;
    (void)in_sizes; (void)n_in; (void)out_size; (void)ws_size;

    // -------- workspace carve (bytes, 16B aligned); total ~171 MB --------
    char* base = (char*)d_ws;
    size_t o = 0;
    auto carve = [&](size_t bytes) { char* p = base + o; o += (bytes + 15) & ~(size_t)15; return p; };
    float* x_cl    = (float*)carve(8388608);      // [2048][1024] f32 (proj out, channels-last)
    u16*   imT     = (u16*)  carve(8388608);      // [8*256][2048] bf16
    u16*   convout = (u16*)  carve(12845056);     // [512][12544] bf16
    float* fc_out  = (float*)carve(2097152);      // [512][1024] f32 (atomic acc)
    u16*   feats   = (u16*)  carve(1310720);      // [512][1280] bf16
    float* UV      = (float*)carve(5242880);      // [512][2560] f32 (atomic acc)
    u16*   wpack   = (u16*)  carve(4718592);      // [256][9216] bf16
    float* scale   = (float*)carve(1024);
    float* shift   = (float*)carve(1024);
    u16*   projwb  = (u16*)  carve(4194304);      // [1024][2048] bf16
    u16*   fcwb    = (u16*)  carve(25690112);     // [1024][12544] bf16
    u16*   g1wb    = (u16*)  carve(6553600);      // [2560][1280] bf16
    u16*   g2wb    = (u16*)  carve(3276800);      // [1280][1280] bf16
    u16*   g3wb    = (u16*)  carve(3276800);      // [1280][1280] bf16
    char*  big     = carve(84934656);             // r_pad [512][81][1024] bf16; later h1+h2
    u16*   r_pad   = (u16*)big;
    u16*   h1      = (u16*)big;                   // [16384][1280] bf16 (after conv GEMM done)
    u16*   h2      = (u16*)(big + 41943040);      // [16384][1280] bf16

    // -------- zero accumulators --------
    zero_f32<<<40, 256, 0, stream>>>(out, 10240);
    zero_f32<<<2048, 256, 0, stream>>>(fc_out, 524288);
    zero_f32<<<5120, 256, 0, stream>>>(UV, 1310720);

    // -------- weight conversion / packing --------
    cvt_bf16<<<2048, 256, 0, stream>>>(proj_w, projwb, 524288);
    cvt_bf16<<<12544, 256, 0, stream>>>(fc_w, fcwb, 3211264);
    cvt_bf16<<<1600, 256, 0, stream>>>(g2_w, g2wb, 409600);
    cvt_bf16<<<1600, 256, 0, stream>>>(g3_w, g3wb, 409600);
    pack_g1<<<3200, 256, 0, stream>>>(g1_w, g1wb);
    pack_conv<<<9216, 256, 0, stream>>>(conv_w, conv_b, bn_g, bn_b, bn_m, bn_v, wpack, scale, shift);

    // -------- 1x1 projection: transpose to bf16 then MFMA GEMM --------
    transpose_proj<<<dim3(4, 32, 8), 256, 0, stream>>>(im_feat, imT);
    gemm_bf16<0, 1, 0><<<dim3(8, 16, 1), 256, 0, stream>>>(
        imT, projwb, proj_b, nullptr, x_cl, 2048, 1024, 2048, 2048, 2048, 1024);

    // -------- ROIAlign into zero-padded bf16 buffer --------
    zero_halo<<<16384, 256, 0, stream>>>(r_pad);
    roialign_kernel<<<25088, 256, 0, stream>>>(x_cl, boxes, r_pad);

    // -------- conv3x3 + BN + ReLU (im2col MFMA), scatter to [roi][oc*49+sp] bf16 --------
    gemm_bf16<2, 3, 1><<<dim3(2, 196, 1), 256, 0, stream>>>(
        r_pad, wpack, scale, shift, convout, 25088, 256, 9216, 0, 9216, 0);

    // -------- FC (split-K 4, atomic f32): raw sum; bias+relu fused into LN1 --------
    gemm_bf16<0, 0, 3><<<dim3(8, 4, 4), 256, 0, stream>>>(
        convout, fcwb, nullptr, nullptr, fc_out, 512, 1024, 3136, 12544, 12544, 1024);

    ln1_kernel<<<512, 256, 0, stream>>>(fc_out, fc_b, ln1_g, ln1_b, feats);
    box_kernel<<<512, 256, 0, stream>>>(nboxes, box_w, box_b, ln2_g, ln2_b, feats);

    // -------- U/V GEMM (split-K 2, atomic f32): UV[m][n<1280]=U, UV[m][1280+n]=V --------
    gemm_bf16<0, 0, 3><<<dim3(20, 4, 2), 256, 0, stream>>>(
        feats, g1wb, nullptr, nullptr, UV, 512, 2560, 640, 1280, 1280, 2560);

    // -------- relation: 2 chunks of 4 images --------
    for (int h = 0; h < 2; ++h) {
        pair_kernel<<<dim3(5, 16384), 256, 0, stream>>>(UV, g1_b, h1, h * 4);
        gemm_bf16<0, 2, 4><<<dim3(10, 128, 1), 256, 0, stream>>>(
            h1, g2wb, g2_b, nullptr, h2, 16384, 1280, 1280, 1280, 1280, 1280);
        gemm_bf16<0, 2, 2><<<dim3(10, 128, 1), 256, 0, stream>>>(
            h2, g3wb, g3_b, nullptr, out + h * 4 * 1280, 16384, 1280, 1280, 1280, 1280, 1280);
    }
}